// Round 14
// baseline (428.807 us; speedup 1.0000x reference)
//
#include <hip/hip_runtime.h>
#include <hip/hip_bf16.h>

typedef __attribute__((ext_vector_type(8))) _Float16 half8;
typedef __attribute__((ext_vector_type(4))) _Float16 half4v;
typedef __attribute__((ext_vector_type(4))) float f32x4;

__device__ __forceinline__ float wred_max(float v){
  #pragma unroll
  for (int o = 32; o; o >>= 1) v = fmaxf(v, __shfl_xor(v, o));
  return v;
}
__device__ __forceinline__ float wred_sum(float v){
  #pragma unroll
  for (int o = 32; o; o >>= 1) v += __shfl_xor(v, o);
  return v;
}
__device__ __forceinline__ unsigned short h2u(_Float16 h){
  unsigned short u;
  __builtin_memcpy(&u, &h, 2);
  return u;
}
__device__ __forceinline__ float u2hf(unsigned short u){
  _Float16 h;
  __builtin_memcpy(&h, &u, 2);
  return (float)h;
}

#define GLOAD16(GP, LP) __builtin_amdgcn_global_load_lds( \
    (const __attribute__((address_space(1))) void*)(GP),  \
    (__attribute__((address_space(3))) void*)(LP), 16, 0, 0)

// ======== MFMA GEMM, 2-phase double-buffered: C = alpha * A @ B^T (+bias) ========
template<int BM, int BN, int OUT_F16, int ACT>
__global__ __launch_bounds__(256) void gemm_ht(
    const _Float16* __restrict__ A, long saz, int lda,
    const _Float16* __restrict__ B, long sbz, int ldb,
    void* __restrict__ Cv, long scz, int ldc,
    int K, float alpha, const float* __restrict__ bias)
{
  constexpr int FM = BM / 32, FN = BN / 32;
  __shared__ __align__(16) _Float16 Asl[2][BM * 32];
  __shared__ __align__(16) _Float16 Bsl[2][BN * 32];
  const int t = threadIdx.x;
  const int wid = t >> 6, lane = t & 63;
  const int wr = wid >> 1, wc = wid & 1;
  const int lr = lane & 15, kg = lane >> 4;
  A += (long)blockIdx.z * saz;
  B += (long)blockIdx.z * sbz;
  const long row0 = (long)blockIdx.y * BM;
  const long col0 = (long)blockIdx.x * BN;

  const int arow_t = t >> 2, acol_t = (t & 3) * 8;

  auto stage = [&](int buf, int k0){
    #pragma unroll
    for (int r = 0; r < BM / 64; r++){
      const _Float16* gp = A + (row0 + r*64 + arow_t) * (long)lda + k0 + acol_t;
      GLOAD16(gp, (char*)Asl[buf] + r*4096 + wid*1024);
    }
    #pragma unroll
    for (int r = 0; r < BN / 64; r++){
      const _Float16* gp = B + (col0 + r*64 + arow_t) * (long)ldb + k0 + acol_t;
      GLOAD16(gp, (char*)Bsl[buf] + r*4096 + wid*1024);
    }
  };

  f32x4 acc[FM][FN];
  #pragma unroll
  for (int i = 0; i < FM; i++)
    #pragma unroll
    for (int j = 0; j < FN; j++)
      acc[i][j] = (f32x4){0.f, 0.f, 0.f, 0.f};

  stage(0, 0);
  __syncthreads();
  int cur = 0;
  for (int k0 = 0; k0 < K; k0 += 32){
    if (k0 + 32 < K) stage(cur ^ 1, k0 + 32);
    half8 af[FM], bfv[FN];
    #pragma unroll
    for (int i = 0; i < FM; i++)
      af[i] = *(const half8*)((const char*)Asl[cur] + (wr*(BM/2) + i*16 + lr)*64 + kg*16);
    #pragma unroll
    for (int j = 0; j < FN; j++)
      bfv[j] = *(const half8*)((const char*)Bsl[cur] + (wc*(BN/2) + j*16 + lr)*64 + kg*16);
    #pragma unroll
    for (int i = 0; i < FM; i++)
      #pragma unroll
      for (int j = 0; j < FN; j++)
        acc[i][j] = __builtin_amdgcn_mfma_f32_16x16x32_f16(af[i], bfv[j], acc[i][j], 0, 0, 0);
    __syncthreads();
    cur ^= 1;
  }

  _Float16* Ch = (_Float16*)Cv + (long)blockIdx.z * scz;
  float*    Cf = (float*)Cv    + (long)blockIdx.z * scz;
  #pragma unroll
  for (int i = 0; i < FM; i++){
    #pragma unroll
    for (int j = 0; j < FN; j++){
      #pragma unroll
      for (int q = 0; q < 4; q++){
        long rr = row0 + wr*(BM/2) + i*16 + kg*4 + q;
        long cc = col0 + wc*(BN/2) + j*16 + lr;
        float val = acc[i][j][q] * alpha;
        if (bias) val += bias[cc];
        if constexpr (ACT) val = 0.5f * val * (1.0f + erff(val * 0.70710678118654752f));
        if constexpr (OUT_F16) Ch[rr*(long)ldc + cc] = (_Float16)val;
        else                   Cf[rr*(long)ldc + cc] = val;
      }
    }
  }
}

// ======== PV GEMM, 2-phase dbuf, fused exp/mask on A (reg-staged, write-late) ========
template<int BM, int BN, int SPARSE>
__global__ __launch_bounds__(256) void gemm_pv_exp(
    const _Float16* __restrict__ A, long saz, int lda,
    const _Float16* __restrict__ B, long sbz, int ldb,
    const float4* __restrict__ mlthr,
    _Float16* __restrict__ Ph, int nsplit, int Ksplit)
{
  constexpr int FM = BM / 32, FN = BN / 32;
  __shared__ __align__(16) _Float16 Asl[2][BM * 32];
  __shared__ __align__(16) _Float16 Bsl[2][BN * 32];
  const int t = threadIdx.x;
  const int wid = t >> 6, lane = t & 63;
  const int wr = wid >> 1, wc = wid & 1;
  const int lr = lane & 15, kg = lane >> 4;
  const int z = blockIdx.z, batch = z / nsplit, split = z % nsplit;
  A += (long)batch * saz;
  B += (long)batch * sbz;
  _Float16* Pz = Ph + (size_t)z * (4096 * 256);
  const long row0 = (long)blockIdx.y * BM;
  const int Kbase = split * Ksplit;

  const long arow = row0 + (t >> 2);
  const float4 mt = mlthr[(long)batch*4096 + arow];
  const float m = mt.x, thr = mt.z;
  const _Float16* Ap = A + arow * (long)lda + Kbase + (t & 3) * 8;

  const int arow_t = t >> 2, acol_t = (t & 3) * 8;

  auto stageB = [&](int buf, int k0){
    #pragma unroll
    for (int r = 0; r < BN / 64; r++){
      const _Float16* gp = B + (r*64 + arow_t) * (long)ldb + Kbase + k0 + acol_t;
      GLOAD16(gp, (char*)Bsl[buf] + r*4096 + wid*1024);
    }
  };
  auto expw = [&](int buf, half8 ld){
    half8 st;
    #pragma unroll
    for (int e = 0; e < 8; e++){
      float v = (float)ld[e];
      float ev;
      if constexpr (SPARSE) ev = (v >= thr) ? __expf(v - m) : 0.f;
      else                  ev = __expf(v - m);
      st[e] = (_Float16)ev;
    }
    *(half8*)((char*)Asl[buf] + t*16) = st;
  };

  f32x4 acc[FM][FN];
  #pragma unroll
  for (int i = 0; i < FM; i++)
    #pragma unroll
    for (int j = 0; j < FN; j++)
      acc[i][j] = (f32x4){0.f, 0.f, 0.f, 0.f};

  stageB(0, 0);
  expw(0, *(const half8*)(Ap + 0));
  __syncthreads();
  int cur = 0;
  for (int k0 = 0; k0 < Ksplit; k0 += 32){
    const bool more = (k0 + 32 < Ksplit);
    half8 lda_next;
    if (more){
      stageB(cur ^ 1, k0 + 32);
      lda_next = *(const half8*)(Ap + k0 + 32);
    }
    half8 af[FM], bfv[FN];
    #pragma unroll
    for (int i = 0; i < FM; i++)
      af[i] = *(const half8*)((const char*)Asl[cur] + (wr*(BM/2) + i*16 + lr)*64 + kg*16);
    #pragma unroll
    for (int j = 0; j < FN; j++)
      bfv[j] = *(const half8*)((const char*)Bsl[cur] + (wc*(BN/2) + j*16 + lr)*64 + kg*16);
    #pragma unroll
    for (int i = 0; i < FM; i++)
      #pragma unroll
      for (int j = 0; j < FN; j++)
        acc[i][j] = __builtin_amdgcn_mfma_f32_16x16x32_f16(af[i], bfv[j], acc[i][j], 0, 0, 0);
    if (more) expw(cur ^ 1, lda_next);
    __syncthreads();
    cur ^= 1;
  }

  #pragma unroll
  for (int i = 0; i < FM; i++)
    #pragma unroll
    for (int j = 0; j < FN; j++)
      #pragma unroll
      for (int q = 0; q < 4; q++){
        long rr = row0 + wr*(BM/2) + i*16 + kg*4 + q;
        long cc = wc*(BN/2) + j*16 + lr;
        Pz[rr*256 + cc] = (_Float16)acc[i][j][q];
      }
}

// ======== sum 8 f16 partials, divide by l -> f16 comb at column offset ========
__global__ __launch_bounds__(256) void reduce8h(const _Float16* __restrict__ Ph,
                                                const float4* __restrict__ mlthr,
                                                _Float16* __restrict__ dst, int coff, int nq){
  int i = blockIdx.x * 256 + threadIdx.x;
  if (i >= nq) return;
  int b = i >> 18;
  int r = i & 262143;
  int row = r >> 6, col4 = r & 63;
  float sx = 0.f, sy = 0.f, sz = 0.f, sw = 0.f;
  #pragma unroll
  for (int sp = 0; sp < 8; sp++){
    half4v p = *(const half4v*)(Ph + (((size_t)(b*8 + sp)*4096 + row)*256 + col4*4));
    sx += (float)p[0]; sy += (float)p[1]; sz += (float)p[2]; sw += (float)p[3];
  }
  const float inv = 1.0f / mlthr[(long)b*4096 + row].y;
  half4v o;
  o[0] = (_Float16)(sx*inv); o[1] = (_Float16)(sy*inv);
  o[2] = (_Float16)(sz*inv); o[3] = (_Float16)(sw*inv);
  *(half4v*)(dst + ((size_t)b*4096 + row)*1024 + coff + col4*4) = o;
}

// ======== cast f32 -> f16 (8 elems/thread) ========
__global__ __launch_bounds__(256) void cast_xh(const float* __restrict__ in,
                                               _Float16* __restrict__ out, int n8){
  int i = blockIdx.x * 256 + threadIdx.x;
  const int stride = gridDim.x * 256;
  for (; i < n8; i += stride){
    float4 a = ((const float4*)in)[2*i];
    float4 b = ((const float4*)in)[2*i + 1];
    half8 o;
    o[0]=(_Float16)a.x; o[1]=(_Float16)a.y; o[2]=(_Float16)a.z; o[3]=(_Float16)a.w;
    o[4]=(_Float16)b.x; o[5]=(_Float16)b.y; o[6]=(_Float16)b.z; o[7]=(_Float16)b.w;
    *(half8*)(out + (size_t)i*8) = o;
  }
}

// ======== transpose+cast weight: in (R x C) f32 -> out (C x R) f16 ========
__global__ __launch_bounds__(256) void transpose_cast_w(const float* __restrict__ in, int R, int C,
                                                        _Float16* __restrict__ out){
  __shared__ float tile[32][33];
  const int c0 = blockIdx.x * 32, r0 = blockIdx.y * 32;
  const int tx = threadIdx.x & 31, ty = threadIdx.x >> 5;
  #pragma unroll
  for (int i = 0; i < 32; i += 8)
    tile[ty+i][tx] = in[(size_t)(r0+ty+i)*C + c0+tx];
  __syncthreads();
  #pragma unroll
  for (int i = 0; i < 32; i += 8)
    out[(size_t)(c0+ty+i)*R + r0+tx] = (_Float16)tile[tx][ty+i];
}

// ======== f16 transpose: in (R x C, ld_in) -> out (C x R, ld_out), z-batched ========
__global__ __launch_bounds__(256) void transpose_h(
    const _Float16* __restrict__ in, long in_z, int ld_in,
    _Float16* __restrict__ out, long out_z, int ld_out)
{
  __shared__ _Float16 tile[32][34];
  const _Float16* ip = in + (long)blockIdx.z * in_z;
  _Float16* op = out + (long)blockIdx.z * out_z;
  const int c0 = blockIdx.x * 32, r0 = blockIdx.y * 32;
  const int tx = threadIdx.x & 31, ty = threadIdx.x >> 5;
  #pragma unroll
  for (int i = 0; i < 32; i += 8)
    tile[ty+i][tx] = ip[(long)(r0+ty+i)*ld_in + c0+tx];
  __syncthreads();
  #pragma unroll
  for (int i = 0; i < 32; i += 8)
    op[(long)(c0+ty+i)*ld_out + r0+tx] = tile[tx][ty+i];
}

// ======== rowstat (local): m = rowmax, l = sum exp(v-m); read-only ========
__global__ __launch_bounds__(256) void rowstat_local(const _Float16* __restrict__ sc,
                                                     float4* __restrict__ mlthr){
  __shared__ float red[4], red2[4];
  const int t = threadIdx.x, lane = t & 63, wid = t >> 6;
  const _Float16* p = sc + (size_t)blockIdx.x * 4096;
  half8 a = ((const half8*)p)[t*2];
  half8 b = ((const half8*)p)[t*2 + 1];
  float v[16];
  #pragma unroll
  for (int e = 0; e < 8; e++){ v[e] = (float)a[e]; v[8+e] = (float)b[e]; }
  float m = v[0];
  #pragma unroll
  for (int e = 1; e < 16; e++) m = fmaxf(m, v[e]);
  m = wred_max(m);
  if (lane == 0) red[wid] = m;
  __syncthreads();
  m = fmaxf(fmaxf(red[0], red[1]), fmaxf(red[2], red[3]));
  float s = 0.f;
  #pragma unroll
  for (int e = 0; e < 16; e++) s += __expf(v[e] - m);
  s = wred_sum(s);
  if (lane == 0) red2[wid] = s;
  __syncthreads();
  if (t == 0){
    s = red2[0] + red2[1] + red2[2] + red2[3];
    mlthr[blockIdx.x] = make_float4(m, s, -3.0e38f, 0.f);
  }
}

// ======== rowstat (sparse): exact top-k threshold (11-bit + 5-bit radix on u16 keys) ========
// outputs {m, l_masked, thr_value}; read-only over scores.
__global__ __launch_bounds__(256) void rowstat_sparse(const _Float16* __restrict__ sc,
                                                      float4* __restrict__ mlthr, int ksel){
  __shared__ unsigned hist4w[4][2048];   // per-wave 11-bit histograms (32KB)
  __shared__ unsigned svals[256];
  __shared__ unsigned tsum[257];
  __shared__ unsigned wtot[4];
  __shared__ int selb;
  __shared__ unsigned selsuf;
  __shared__ float red[4], red2[4];
  const int t = threadIdx.x, lane = t & 63, wid = t >> 6;
  const _Float16* p = sc + (size_t)blockIdx.x * 4096;
  half8 a = ((const half8*)p)[t*2];
  half8 b = ((const half8*)p)[t*2 + 1];
  float v[16]; unsigned kk[16];
  #pragma unroll
  for (int e = 0; e < 8; e++){
    unsigned short u0 = h2u(a[e]);
    unsigned short u1 = h2u(b[e]);
    kk[e]   = (u0 & 0x8000u) ? (unsigned)(unsigned short)~u0 : (unsigned)(u0 | 0x8000u);
    kk[8+e] = (u1 & 0x8000u) ? (unsigned)(unsigned short)~u1 : (unsigned)(u1 | 0x8000u);
    v[e] = (float)a[e]; v[8+e] = (float)b[e];
  }
  float m = v[0];
  #pragma unroll
  for (int e = 1; e < 16; e++) m = fmaxf(m, v[e]);
  m = wred_max(m);
  if (lane == 0) red[wid] = m;
  __syncthreads();
  m = fmaxf(fmaxf(red[0], red[1]), fmaxf(red[2], red[3]));

  // ---- pass 1: 11-bit prefix (2048 bins), per-wave hist ----
  #pragma unroll
  for (int j = 0; j < 8; j++)
    ((uint4*)hist4w)[t*8 + j] = (uint4){0u,0u,0u,0u};
  __syncthreads();
  #pragma unroll
  for (int e = 0; e < 16; e++) atomicAdd(&hist4w[wid][kk[e] >> 5], 1u);
  __syncthreads();
  unsigned hv[8];
  unsigned s_local = 0;
  #pragma unroll
  for (int j = 0; j < 8; j++){
    hv[j] = hist4w[0][t*8+j] + hist4w[1][t*8+j] + hist4w[2][t*8+j] + hist4w[3][t*8+j];
    s_local += hv[j];
  }
  svals[t] = s_local;
  __syncthreads();
  unsigned x = svals[255 - t];
  #pragma unroll
  for (int o = 1; o < 64; o <<= 1){
    unsigned y = __shfl_up(x, o);
    if (lane >= o) x += y;
  }
  if (lane == 63) wtot[wid] = x;
  __syncthreads();
  #pragma unroll
  for (int w = 0; w < 4; w++) if (w < wid) x += wtot[w];
  tsum[255 - t] = x;            // tsum[t'] = suffix count of bins >= 8*t'
  if (t == 0) tsum[256] = 0u;
  __syncthreads();
  const unsigned ku = (unsigned)ksel;
  {
    unsigned pre = 0;
    #pragma unroll
    for (int j = 0; j < 8; j++){
      unsigned sufj = tsum[t] - pre;                       // suf(8t+j)
      unsigned nxt  = (j == 7) ? tsum[t+1] : (sufj - hv[j]); // suf(8t+j+1)
      if (sufj >= ku && nxt < ku){ selb = t*8 + j; selsuf = nxt; }
      pre += hv[j];
    }
  }
  __syncthreads();
  const int b1 = selb;
  const unsigned rem = ku - selsuf;
  __syncthreads();

  // ---- pass 2: low 5 bits among bin==b1 (reuse first 256 bins of each wave hist) ----
  hist4w[0][t] = 0u; hist4w[1][t] = 0u; hist4w[2][t] = 0u; hist4w[3][t] = 0u;
  __syncthreads();
  #pragma unroll
  for (int e = 0; e < 16; e++)
    if ((int)(kk[e] >> 5) == b1) atomicAdd(&hist4w[wid][kk[e] & 31u], 1u);
  __syncthreads();
  svals[t] = hist4w[0][t] + hist4w[1][t] + hist4w[2][t] + hist4w[3][t];
  __syncthreads();
  x = svals[255 - t];
  #pragma unroll
  for (int o = 1; o < 64; o <<= 1){
    unsigned y = __shfl_up(x, o);
    if (lane >= o) x += y;
  }
  if (lane == 63) wtot[wid] = x;
  __syncthreads();
  #pragma unroll
  for (int w = 0; w < 4; w++) if (w < wid) x += wtot[w];
  tsum[255 - t] = x;
  if (t == 0) tsum[256] = 0u;
  __syncthreads();
  if (tsum[t] >= rem && tsum[t+1] < rem) selb = t;
  __syncthreads();
  const unsigned Tkey = ((unsigned)b1 << 5) | (unsigned)selb;
  const unsigned short tu = (Tkey & 0x8000u) ? (unsigned short)(Tkey & 0x7fffu)
                                             : (unsigned short)~Tkey;
  const float thr = u2hf(tu);

  float s = 0.f;
  #pragma unroll
  for (int e = 0; e < 16; e++)
    s += (v[e] >= thr) ? __expf(v[e] - m) : 0.f;
  s = wred_sum(s);
  if (lane == 0) red2[wid] = s;
  __syncthreads();
  if (t == 0){
    s = red2[0] + red2[1] + red2[2] + red2[3];
    mlthr[blockIdx.x] = make_float4(m, s, thr, 0.f);
  }
}

// ======== memory-head softmax over 64 scores: one wave per row ========
__global__ __launch_bounds__(256) void msoftmax64(const float* __restrict__ mscore,
                                                  _Float16* __restrict__ mprob){
  const int t = threadIdx.x, lane = t & 63, wid = t >> 6;
  const size_t row = (size_t)blockIdx.x * 4 + wid;
  float v = mscore[row*64 + lane];
  float m = wred_max(v);
  float e = expf(v - m);
  float s = wred_sum(e);
  mprob[row*64 + lane] = (_Float16)(e / s);
}

extern "C" void kernel_launch(void* const* d_in, const int* in_sizes, int n_in,
                              void* d_out, int out_size, void* d_ws, size_t ws_size,
                              hipStream_t stream)
{
  const float* x             = (const float*)d_in[0];
  const float* local_qkv_w   = (const float*)d_in[1];
  const float* sparse_qkv_w  = (const float*)d_in[2];
  const float* memory_bank   = (const float*)d_in[3];
  const float* memory_proj_w = (const float*)d_in[4];
  const float* mem_out_w     = (const float*)d_in[5];
  const float* mem_out_b     = (const float*)d_in[6];
  const float* pred_in_w     = (const float*)d_in[7];
  const float* pred_in_b     = (const float*)d_in[8];
  const float* pred1_w       = (const float*)d_in[9];
  const float* pred1_b       = (const float*)d_in[10];
  const float* pred2_w       = (const float*)d_in[11];
  const float* pred2_b       = (const float*)d_in[12];
  const float* warboss_w     = (const float*)d_in[13];
  const float* warboss_b     = (const float*)d_in[14];
  float* out = (float*)d_out;
  _Float16* Ph = (_Float16*)d_out;   // f16 PV partials [16][4096][256] = 33.5MB = d_out

  char* wsb = (char*)d_ws;
  _Float16*  scores_h = (_Float16*)wsb;                // [2][4096][4096] f16 (67MB)
  _Float16*  x_h      = (_Float16*)wsb;
  _Float16*  mem_cat  = (_Float16*)(wsb + 16777216);
  _Float16*  h_in     = (_Float16*)(wsb + 25165824);
  _Float16*  h1       = (_Float16*)(wsb + 29360128);
  float*     mscore   = (float*)(wsb + 37748736);
  _Float16*  mprob    = (_Float16*)(wsb + 39845888);
  _Float16*  qkv_l    = (_Float16*)(wsb + 67108864);   // [8192][768]
  _Float16*  qkv_s    = (_Float16*)(wsb + 79691776);   // [8192][768]
  _Float16*  Vt       = (_Float16*)(wsb + 92274688);   // [2][256][4096]
  _Float16*  comb     = (_Float16*)(wsb + 96468992);   // [8192][1024]
  _Float16*  lqkvT    = (_Float16*)(wsb + 113246208);  // [768][1024]
  _Float16*  sqkvT    = lqkvT  + 786432;
  _Float16*  mprojT   = sqkvT  + 786432;               // [256][1024]
  _Float16*  moutT    = mprojT + 262144;               // [256][512]
  _Float16*  pinT     = moutT  + 131072;               // [256][1024]
  _Float16*  p1T      = pinT   + 262144;               // [512][256]
  _Float16*  p2T      = p1T    + 131072;               // [256][512]
  _Float16*  wbT      = p2T    + 131072;               // [1024][1024]
  _Float16*  bank_h   = wbT    + 1048576;              // [64][256]
  _Float16*  bankT_h  = bank_h + 16384;                // [256][64]
  float4*    mlthr    = (float4*)(bankT_h + 16384);    // [2][4096] {m,l,thr}

  const dim3 blk(256);
  const float scale = 0.0625f;
  const long QZ  = (long)4096 * 768;
  const long VZ  = (long)256 * 4096;
  const long SZH = (long)4096 * 4096;

  // ---- casts / weight transposes ----
  cast_xh<<<dim3(2048), blk, 0, stream>>>(x, x_h, 1048576);
  cast_xh<<<dim3(8), blk, 0, stream>>>(memory_bank, bank_h, 2048);
  transpose_cast_w<<<dim3(24,32), blk, 0, stream>>>(local_qkv_w,  1024,  768, lqkvT);
  transpose_cast_w<<<dim3(24,32), blk, 0, stream>>>(sparse_qkv_w, 1024,  768, sqkvT);
  transpose_cast_w<<<dim3( 8,32), blk, 0, stream>>>(memory_proj_w,1024,  256, mprojT);
  transpose_cast_w<<<dim3( 8,16), blk, 0, stream>>>(mem_out_w,     512,  256, moutT);
  transpose_cast_w<<<dim3( 8,32), blk, 0, stream>>>(pred_in_w,    1024,  256, pinT);
  transpose_cast_w<<<dim3(16, 8), blk, 0, stream>>>(pred1_w,       256,  512, p1T);
  transpose_cast_w<<<dim3( 8,16), blk, 0, stream>>>(pred2_w,       512,  256, p2T);
  transpose_cast_w<<<dim3(32,32), blk, 0, stream>>>(warboss_w,    1024, 1024, wbT);
  transpose_cast_w<<<dim3( 8, 2), blk, 0, stream>>>(memory_bank,    64,  256, bankT_h);

  // ---- QKV projections (merged z=2: local / sparse) ----
  gemm_ht<128,128,1,0><<<dim3(6,64,2), blk, 0, stream>>>(x_h,0,1024, lqkvT,786432,1024,
                                                         qkv_l,6291456,768, 1024, 1.f, nullptr);

  // ---- memory head (GEMM chain) -> comb[:, 512:768] ----
  gemm_ht<64,64,1,0><<<dim3(4,128), blk, 0, stream>>>(x_h,0,1024, mprojT,0,1024, mem_cat,0,512, 1024, 1.f, nullptr);
  gemm_ht<64,64,0,0><<<dim3(1,128), blk, 0, stream>>>(mem_cat,0,512, bank_h,0,256, (void*)mscore,0,64, 256, 1.f, nullptr);
  msoftmax64<<<dim3(2048), blk, 0, stream>>>(mscore, mprob);
  gemm_ht<64,64,1,0><<<dim3(4,128), blk, 0, stream>>>(mprob,0,64, bankT_h,0,64, mem_cat+256,0,512, 64, 1.f, nullptr);
  gemm_ht<64,64,1,0><<<dim3(4,128), blk, 0, stream>>>(mem_cat,0,512, moutT,0,512, comb+512,0,1024, 512, 1.f, mem_out_b);

  // ---- prediction head -> comb[:, 768:1024] ----
  gemm_ht<64,64,1,0><<<dim3(4,128), blk, 0, stream>>>(x_h,0,1024, pinT,0,1024, h_in,0,256, 1024, 1.f, pred_in_b);
  gemm_ht<64,128,1,1><<<dim3(4,128), blk, 0, stream>>>(h_in,0,256, p1T,0,256, h1,0,512, 256, 1.f, pred1_b);
  gemm_ht<64,64,1,0><<<dim3(4,128), blk, 0, stream>>>(h1,0,512, p2T,0,512, comb+768,0,1024, 512, 1.f, pred2_b);

  // ---- local (full) attention -> comb[:, 0:256] ----
  transpose_h<<<dim3(8,128,2), blk, 0, stream>>>(qkv_l+512, QZ, 768, Vt, VZ, 4096);
  gemm_ht<128,128,1,0><<<dim3(32,32,2), blk, 0, stream>>>(qkv_l,QZ,768, qkv_l+256,QZ,768,
                                                          (void*)scores_h,SZH,4096, 256, scale, nullptr);
  rowstat_local<<<dim3(8192), blk, 0, stream>>>(scores_h, mlthr);
  gemm_pv_exp<64,256,0><<<dim3(1,64,16), blk, 0, stream>>>(scores_h,SZH,4096, Vt,VZ,4096, mlthr, Ph, 8, 512);
  reduce8h<<<dim3(2048), blk, 0, stream>>>(Ph, mlthr, comb, 0, 524288);

  // ---- sparse (top-k) attention -> comb[:, 256:512] ----
  transpose_h<<<dim3(8,128,2), blk, 0, stream>>>(qkv_s+512, QZ, 768, Vt, VZ, 4096);
  gemm_ht<128,128,1,0><<<dim3(32,32,2), blk, 0, stream>>>(qkv_s,QZ,768, qkv_s+256,QZ,768,
                                                          (void*)scores_h,SZH,4096, 256, scale, nullptr);
  rowstat_sparse<<<dim3(8192), blk, 0, stream>>>(scores_h, mlthr, 409);
  gemm_pv_exp<64,256,1><<<dim3(1,64,16), blk, 0, stream>>>(scores_h,SZH,4096, Vt,VZ,4096, mlthr, Ph, 8, 512);
  reduce8h<<<dim3(2048), blk, 0, stream>>>(Ph, mlthr, comb, 256, 524288);

  // ---- output projection (f32 out; overwrites the Ph scratch region) ----
  gemm_ht<128,128,0,0><<<dim3(8,64), blk, 0, stream>>>(comb,0,1024, wbT,0,1024, (void*)out,0,1024, 1024, 1.f, warboss_b);
}

// Round 15
// 398.653 us; speedup vs baseline: 1.0756x; 1.0756x over previous
//
#include <hip/hip_runtime.h>
#include <hip/hip_bf16.h>

typedef __attribute__((ext_vector_type(8))) _Float16 half8;
typedef __attribute__((ext_vector_type(4))) _Float16 half4v;
typedef __attribute__((ext_vector_type(4))) float f32x4;

__device__ __forceinline__ float wred_max(float v){
  #pragma unroll
  for (int o = 32; o; o >>= 1) v = fmaxf(v, __shfl_xor(v, o));
  return v;
}
__device__ __forceinline__ float wred_sum(float v){
  #pragma unroll
  for (int o = 32; o; o >>= 1) v += __shfl_xor(v, o);
  return v;
}
__device__ __forceinline__ unsigned short h2u(_Float16 h){
  unsigned short u;
  __builtin_memcpy(&u, &h, 2);
  return u;
}
__device__ __forceinline__ float u2hf(unsigned short u){
  _Float16 h;
  __builtin_memcpy(&h, &u, 2);
  return (float)h;
}

#define GLOAD16(GP, LP) __builtin_amdgcn_global_load_lds( \
    (const __attribute__((address_space(1))) void*)(GP),  \
    (__attribute__((address_space(3))) void*)(LP), 16, 0, 0)

// ======== MFMA GEMM, 2-phase double-buffered: C = alpha * A @ B^T (+bias) ========
template<int BM, int BN, int OUT_F16, int ACT>
__global__ __launch_bounds__(256) void gemm_ht(
    const _Float16* __restrict__ A, long saz, int lda,
    const _Float16* __restrict__ B, long sbz, int ldb,
    void* __restrict__ Cv, long scz, int ldc,
    int K, float alpha, const float* __restrict__ bias)
{
  constexpr int FM = BM / 32, FN = BN / 32;
  __shared__ __align__(16) _Float16 Asl[2][BM * 32];
  __shared__ __align__(16) _Float16 Bsl[2][BN * 32];
  const int t = threadIdx.x;
  const int wid = t >> 6, lane = t & 63;
  const int wr = wid >> 1, wc = wid & 1;
  const int lr = lane & 15, kg = lane >> 4;
  A += (long)blockIdx.z * saz;
  B += (long)blockIdx.z * sbz;
  const long row0 = (long)blockIdx.y * BM;
  const long col0 = (long)blockIdx.x * BN;

  const int arow_t = t >> 2, acol_t = (t & 3) * 8;

  auto stage = [&](int buf, int k0){
    #pragma unroll
    for (int r = 0; r < BM / 64; r++){
      const _Float16* gp = A + (row0 + r*64 + arow_t) * (long)lda + k0 + acol_t;
      GLOAD16(gp, (char*)Asl[buf] + r*4096 + wid*1024);
    }
    #pragma unroll
    for (int r = 0; r < BN / 64; r++){
      const _Float16* gp = B + (col0 + r*64 + arow_t) * (long)ldb + k0 + acol_t;
      GLOAD16(gp, (char*)Bsl[buf] + r*4096 + wid*1024);
    }
  };

  f32x4 acc[FM][FN];
  #pragma unroll
  for (int i = 0; i < FM; i++)
    #pragma unroll
    for (int j = 0; j < FN; j++)
      acc[i][j] = (f32x4){0.f, 0.f, 0.f, 0.f};

  stage(0, 0);
  __syncthreads();
  int cur = 0;
  for (int k0 = 0; k0 < K; k0 += 32){
    if (k0 + 32 < K) stage(cur ^ 1, k0 + 32);
    half8 af[FM], bfv[FN];
    #pragma unroll
    for (int i = 0; i < FM; i++)
      af[i] = *(const half8*)((const char*)Asl[cur] + (wr*(BM/2) + i*16 + lr)*64 + kg*16);
    #pragma unroll
    for (int j = 0; j < FN; j++)
      bfv[j] = *(const half8*)((const char*)Bsl[cur] + (wc*(BN/2) + j*16 + lr)*64 + kg*16);
    #pragma unroll
    for (int i = 0; i < FM; i++)
      #pragma unroll
      for (int j = 0; j < FN; j++)
        acc[i][j] = __builtin_amdgcn_mfma_f32_16x16x32_f16(af[i], bfv[j], acc[i][j], 0, 0, 0);
    __syncthreads();
    cur ^= 1;
  }

  _Float16* Ch = (_Float16*)Cv + (long)blockIdx.z * scz;
  float*    Cf = (float*)Cv    + (long)blockIdx.z * scz;
  #pragma unroll
  for (int i = 0; i < FM; i++){
    #pragma unroll
    for (int j = 0; j < FN; j++){
      #pragma unroll
      for (int q = 0; q < 4; q++){
        long rr = row0 + wr*(BM/2) + i*16 + kg*4 + q;
        long cc = col0 + wc*(BN/2) + j*16 + lr;
        float val = acc[i][j][q] * alpha;
        if (bias) val += bias[cc];
        if constexpr (ACT) val = 0.5f * val * (1.0f + erff(val * 0.70710678118654752f));
        if constexpr (OUT_F16) Ch[rr*(long)ldc + cc] = (_Float16)val;
        else                   Cf[rr*(long)ldc + cc] = val;
      }
    }
  }
}

// ======== PV GEMM, 2-phase dbuf, fused exp/mask on A (reg-staged, write-late) ========
template<int BM, int BN, int SPARSE>
__global__ __launch_bounds__(256) void gemm_pv_exp(
    const _Float16* __restrict__ A, long saz, int lda,
    const _Float16* __restrict__ B, long sbz, int ldb,
    const float4* __restrict__ mlthr,
    _Float16* __restrict__ Ph, int nsplit, int Ksplit)
{
  constexpr int FM = BM / 32, FN = BN / 32;
  __shared__ __align__(16) _Float16 Asl[2][BM * 32];
  __shared__ __align__(16) _Float16 Bsl[2][BN * 32];
  const int t = threadIdx.x;
  const int wid = t >> 6, lane = t & 63;
  const int wr = wid >> 1, wc = wid & 1;
  const int lr = lane & 15, kg = lane >> 4;
  const int z = blockIdx.z, batch = z / nsplit, split = z % nsplit;
  A += (long)batch * saz;
  B += (long)batch * sbz;
  _Float16* Pz = Ph + (size_t)z * (4096 * 256);
  const long row0 = (long)blockIdx.y * BM;
  const int Kbase = split * Ksplit;

  const long arow = row0 + (t >> 2);
  const float4 mt = mlthr[(long)batch*4096 + arow];
  const float m = mt.x, thr = mt.z;
  const _Float16* Ap = A + arow * (long)lda + Kbase + (t & 3) * 8;

  const int arow_t = t >> 2, acol_t = (t & 3) * 8;

  auto stageB = [&](int buf, int k0){
    #pragma unroll
    for (int r = 0; r < BN / 64; r++){
      const _Float16* gp = B + (r*64 + arow_t) * (long)ldb + Kbase + k0 + acol_t;
      GLOAD16(gp, (char*)Bsl[buf] + r*4096 + wid*1024);
    }
  };
  auto expw = [&](int buf, half8 ld){
    half8 st;
    #pragma unroll
    for (int e = 0; e < 8; e++){
      float v = (float)ld[e];
      float ev;
      if constexpr (SPARSE) ev = (v >= thr) ? __expf(v - m) : 0.f;
      else                  ev = __expf(v - m);
      st[e] = (_Float16)ev;
    }
    *(half8*)((char*)Asl[buf] + t*16) = st;
  };

  f32x4 acc[FM][FN];
  #pragma unroll
  for (int i = 0; i < FM; i++)
    #pragma unroll
    for (int j = 0; j < FN; j++)
      acc[i][j] = (f32x4){0.f, 0.f, 0.f, 0.f};

  stageB(0, 0);
  expw(0, *(const half8*)(Ap + 0));
  __syncthreads();
  int cur = 0;
  for (int k0 = 0; k0 < Ksplit; k0 += 32){
    const bool more = (k0 + 32 < Ksplit);
    half8 lda_next;
    if (more){
      stageB(cur ^ 1, k0 + 32);
      lda_next = *(const half8*)(Ap + k0 + 32);
    }
    half8 af[FM], bfv[FN];
    #pragma unroll
    for (int i = 0; i < FM; i++)
      af[i] = *(const half8*)((const char*)Asl[cur] + (wr*(BM/2) + i*16 + lr)*64 + kg*16);
    #pragma unroll
    for (int j = 0; j < FN; j++)
      bfv[j] = *(const half8*)((const char*)Bsl[cur] + (wc*(BN/2) + j*16 + lr)*64 + kg*16);
    #pragma unroll
    for (int i = 0; i < FM; i++)
      #pragma unroll
      for (int j = 0; j < FN; j++)
        acc[i][j] = __builtin_amdgcn_mfma_f32_16x16x32_f16(af[i], bfv[j], acc[i][j], 0, 0, 0);
    if (more) expw(cur ^ 1, lda_next);
    __syncthreads();
    cur ^= 1;
  }

  #pragma unroll
  for (int i = 0; i < FM; i++)
    #pragma unroll
    for (int j = 0; j < FN; j++)
      #pragma unroll
      for (int q = 0; q < 4; q++){
        long rr = row0 + wr*(BM/2) + i*16 + kg*4 + q;
        long cc = wc*(BN/2) + j*16 + lr;
        Pz[rr*256 + cc] = (_Float16)acc[i][j][q];
      }
}

// ======== sum 8 f16 partials, divide by l -> f16 comb at column offset ========
__global__ __launch_bounds__(256) void reduce8h(const _Float16* __restrict__ Ph,
                                                const float4* __restrict__ mlthr,
                                                _Float16* __restrict__ dst, int coff, int nq){
  int i = blockIdx.x * 256 + threadIdx.x;
  if (i >= nq) return;
  int b = i >> 18;
  int r = i & 262143;
  int row = r >> 6, col4 = r & 63;
  float sx = 0.f, sy = 0.f, sz = 0.f, sw = 0.f;
  #pragma unroll
  for (int sp = 0; sp < 8; sp++){
    half4v p = *(const half4v*)(Ph + (((size_t)(b*8 + sp)*4096 + row)*256 + col4*4));
    sx += (float)p[0]; sy += (float)p[1]; sz += (float)p[2]; sw += (float)p[3];
  }
  const float inv = 1.0f / mlthr[(long)b*4096 + row].y;
  half4v o;
  o[0] = (_Float16)(sx*inv); o[1] = (_Float16)(sy*inv);
  o[2] = (_Float16)(sz*inv); o[3] = (_Float16)(sw*inv);
  *(half4v*)(dst + ((size_t)b*4096 + row)*1024 + coff + col4*4) = o;
}

// ======== cast f32 -> f16 (8 elems/thread) ========
__global__ __launch_bounds__(256) void cast_xh(const float* __restrict__ in,
                                               _Float16* __restrict__ out, int n8){
  int i = blockIdx.x * 256 + threadIdx.x;
  const int stride = gridDim.x * 256;
  for (; i < n8; i += stride){
    float4 a = ((const float4*)in)[2*i];
    float4 b = ((const float4*)in)[2*i + 1];
    half8 o;
    o[0]=(_Float16)a.x; o[1]=(_Float16)a.y; o[2]=(_Float16)a.z; o[3]=(_Float16)a.w;
    o[4]=(_Float16)b.x; o[5]=(_Float16)b.y; o[6]=(_Float16)b.z; o[7]=(_Float16)b.w;
    *(half8*)(out + (size_t)i*8) = o;
  }
}

// ======== transpose+cast weight: in (R x C) f32 -> out (C x R) f16 ========
__global__ __launch_bounds__(256) void transpose_cast_w(const float* __restrict__ in, int R, int C,
                                                        _Float16* __restrict__ out){
  __shared__ float tile[32][33];
  const int c0 = blockIdx.x * 32, r0 = blockIdx.y * 32;
  const int tx = threadIdx.x & 31, ty = threadIdx.x >> 5;
  #pragma unroll
  for (int i = 0; i < 32; i += 8)
    tile[ty+i][tx] = in[(size_t)(r0+ty+i)*C + c0+tx];
  __syncthreads();
  #pragma unroll
  for (int i = 0; i < 32; i += 8)
    out[(size_t)(c0+ty+i)*R + r0+tx] = (_Float16)tile[tx][ty+i];
}

// ======== f16 transpose: in (R x C, ld_in) -> out (C x R, ld_out), z-batched ========
__global__ __launch_bounds__(256) void transpose_h(
    const _Float16* __restrict__ in, long in_z, int ld_in,
    _Float16* __restrict__ out, long out_z, int ld_out)
{
  __shared__ _Float16 tile[32][34];
  const _Float16* ip = in + (long)blockIdx.z * in_z;
  _Float16* op = out + (long)blockIdx.z * out_z;
  const int c0 = blockIdx.x * 32, r0 = blockIdx.y * 32;
  const int tx = threadIdx.x & 31, ty = threadIdx.x >> 5;
  #pragma unroll
  for (int i = 0; i < 32; i += 8)
    tile[ty+i][tx] = ip[(long)(r0+ty+i)*ld_in + c0+tx];
  __syncthreads();
  #pragma unroll
  for (int i = 0; i < 32; i += 8)
    op[(long)(c0+ty+i)*ld_out + r0+tx] = tile[tx][ty+i];
}

// ======== rowstat (local): m = rowmax, l = sum exp(v-m); read-only ========
__global__ __launch_bounds__(256) void rowstat_local(const _Float16* __restrict__ sc,
                                                     float4* __restrict__ mlthr){
  __shared__ float red[4], red2[4];
  const int t = threadIdx.x, lane = t & 63, wid = t >> 6;
  const _Float16* p = sc + (size_t)blockIdx.x * 4096;
  half8 a = ((const half8*)p)[t*2];
  half8 b = ((const half8*)p)[t*2 + 1];
  float v[16];
  #pragma unroll
  for (int e = 0; e < 8; e++){ v[e] = (float)a[e]; v[8+e] = (float)b[e]; }
  float m = v[0];
  #pragma unroll
  for (int e = 1; e < 16; e++) m = fmaxf(m, v[e]);
  m = wred_max(m);
  if (lane == 0) red[wid] = m;
  __syncthreads();
  m = fmaxf(fmaxf(red[0], red[1]), fmaxf(red[2], red[3]));
  float s = 0.f;
  #pragma unroll
  for (int e = 0; e < 16; e++) s += __expf(v[e] - m);
  s = wred_sum(s);
  if (lane == 0) red2[wid] = s;
  __syncthreads();
  if (t == 0){
    s = red2[0] + red2[1] + red2[2] + red2[3];
    mlthr[blockIdx.x] = make_float4(m, s, -3.0e38f, 0.f);
  }
}

// ======== rowstat (sparse): exact top-k threshold (2x8-bit radix on u16 keys) ========
// outputs {m, l_masked, thr_value}; read-only over scores.  (R13-proven version)
__global__ __launch_bounds__(256) void rowstat_sparse(const _Float16* __restrict__ sc,
                                                      float4* __restrict__ mlthr, int ksel){
  __shared__ unsigned hist4[4][256];
  __shared__ unsigned hrev[256];
  __shared__ unsigned suf[257];
  __shared__ unsigned wtot[4];
  __shared__ int selb;
  __shared__ float red[4], red2[4];
  const int t = threadIdx.x, lane = t & 63, wid = t >> 6;
  const _Float16* p = sc + (size_t)blockIdx.x * 4096;
  half8 a = ((const half8*)p)[t*2];
  half8 b = ((const half8*)p)[t*2 + 1];
  float v[16]; unsigned kk[16];
  #pragma unroll
  for (int e = 0; e < 8; e++){
    unsigned short u0 = h2u(a[e]);
    unsigned short u1 = h2u(b[e]);
    kk[e]   = (u0 & 0x8000u) ? (unsigned)(unsigned short)~u0 : (unsigned)(u0 | 0x8000u);
    kk[8+e] = (u1 & 0x8000u) ? (unsigned)(unsigned short)~u1 : (unsigned)(u1 | 0x8000u);
    v[e] = (float)a[e]; v[8+e] = (float)b[e];
  }
  float m = v[0];
  #pragma unroll
  for (int e = 1; e < 16; e++) m = fmaxf(m, v[e]);
  m = wred_max(m);
  if (lane == 0) red[wid] = m;
  __syncthreads();
  m = fmaxf(fmaxf(red[0], red[1]), fmaxf(red[2], red[3]));

  // ---- pass 1: high byte ----
  ((uint4*)hist4)[t] = (uint4){0u,0u,0u,0u};
  __syncthreads();
  #pragma unroll
  for (int e = 0; e < 16; e++) atomicAdd(&hist4[wid][kk[e] >> 8], 1u);
  __syncthreads();
  hrev[t] = hist4[0][t] + hist4[1][t] + hist4[2][t] + hist4[3][t];
  __syncthreads();
  unsigned x = hrev[255 - t];
  #pragma unroll
  for (int o = 1; o < 64; o <<= 1){
    unsigned y = __shfl_up(x, o);
    if (lane >= o) x += y;
  }
  if (lane == 63) wtot[wid] = x;
  __syncthreads();
  #pragma unroll
  for (int w = 0; w < 4; w++) if (w < wid) x += wtot[w];
  suf[255 - t] = x;
  if (t == 0) suf[256] = 0u;
  __syncthreads();
  const unsigned ku = (unsigned)ksel;
  if (suf[t] >= ku && suf[t+1] < ku) selb = t;
  __syncthreads();
  const int b1 = selb;
  const unsigned rem = ku - suf[b1+1];
  __syncthreads();

  // ---- pass 2: low byte among high==b1 ----
  ((uint4*)hist4)[t] = (uint4){0u,0u,0u,0u};
  __syncthreads();
  #pragma unroll
  for (int e = 0; e < 16; e++)
    if ((int)(kk[e] >> 8) == b1) atomicAdd(&hist4[wid][kk[e] & 255u], 1u);
  __syncthreads();
  hrev[t] = hist4[0][t] + hist4[1][t] + hist4[2][t] + hist4[3][t];
  __syncthreads();
  x = hrev[255 - t];
  #pragma unroll
  for (int o = 1; o < 64; o <<= 1){
    unsigned y = __shfl_up(x, o);
    if (lane >= o) x += y;
  }
  if (lane == 63) wtot[wid] = x;
  __syncthreads();
  #pragma unroll
  for (int w = 0; w < 4; w++) if (w < wid) x += wtot[w];
  suf[255 - t] = x;
  if (t == 0) suf[256] = 0u;
  __syncthreads();
  if (suf[t] >= rem && suf[t+1] < rem) selb = t;
  __syncthreads();
  const unsigned Tkey = ((unsigned)b1 << 8) | (unsigned)selb;
  const unsigned short tu = (Tkey & 0x8000u) ? (unsigned short)(Tkey & 0x7fffu)
                                             : (unsigned short)~Tkey;
  const float thr = u2hf(tu);

  float s = 0.f;
  #pragma unroll
  for (int e = 0; e < 16; e++)
    s += (v[e] >= thr) ? __expf(v[e] - m) : 0.f;
  s = wred_sum(s);
  if (lane == 0) red2[wid] = s;
  __syncthreads();
  if (t == 0){
    s = red2[0] + red2[1] + red2[2] + red2[3];
    mlthr[blockIdx.x] = make_float4(m, s, thr, 0.f);
  }
}

// ======== memory-head softmax over 64 scores: one wave per row ========
__global__ __launch_bounds__(256) void msoftmax64(const float* __restrict__ mscore,
                                                  _Float16* __restrict__ mprob){
  const int t = threadIdx.x, lane = t & 63, wid = t >> 6;
  const size_t row = (size_t)blockIdx.x * 4 + wid;
  float v = mscore[row*64 + lane];
  float m = wred_max(v);
  float e = expf(v - m);
  float s = wred_sum(e);
  mprob[row*64 + lane] = (_Float16)(e / s);
}

extern "C" void kernel_launch(void* const* d_in, const int* in_sizes, int n_in,
                              void* d_out, int out_size, void* d_ws, size_t ws_size,
                              hipStream_t stream)
{
  const float* x             = (const float*)d_in[0];
  const float* local_qkv_w   = (const float*)d_in[1];
  const float* sparse_qkv_w  = (const float*)d_in[2];
  const float* memory_bank   = (const float*)d_in[3];
  const float* memory_proj_w = (const float*)d_in[4];
  const float* mem_out_w     = (const float*)d_in[5];
  const float* mem_out_b     = (const float*)d_in[6];
  const float* pred_in_w     = (const float*)d_in[7];
  const float* pred_in_b     = (const float*)d_in[8];
  const float* pred1_w       = (const float*)d_in[9];
  const float* pred1_b       = (const float*)d_in[10];
  const float* pred2_w       = (const float*)d_in[11];
  const float* pred2_b       = (const float*)d_in[12];
  const float* warboss_w     = (const float*)d_in[13];
  const float* warboss_b     = (const float*)d_in[14];
  float* out = (float*)d_out;
  _Float16* Ph = (_Float16*)d_out;   // f16 PV partials [16][4096][256] = 33.5MB = d_out

  char* wsb = (char*)d_ws;
  _Float16*  scores_h = (_Float16*)wsb;                // [2][4096][4096] f16 (67MB)
  _Float16*  x_h      = (_Float16*)wsb;
  _Float16*  mem_cat  = (_Float16*)(wsb + 16777216);
  _Float16*  h_in     = (_Float16*)(wsb + 25165824);
  _Float16*  h1       = (_Float16*)(wsb + 29360128);
  float*     mscore   = (float*)(wsb + 37748736);
  _Float16*  mprob    = (_Float16*)(wsb + 39845888);
  _Float16*  qkv_l    = (_Float16*)(wsb + 67108864);   // [8192][768]
  _Float16*  qkv_s    = (_Float16*)(wsb + 79691776);   // [8192][768]
  _Float16*  Vt       = (_Float16*)(wsb + 92274688);   // [2][256][4096]
  _Float16*  comb     = (_Float16*)(wsb + 96468992);   // [8192][1024]
  _Float16*  lqkvT    = (_Float16*)(wsb + 113246208);  // [768][1024]
  _Float16*  sqkvT    = lqkvT  + 786432;
  _Float16*  mprojT   = sqkvT  + 786432;               // [256][1024]
  _Float16*  moutT    = mprojT + 262144;               // [256][512]
  _Float16*  pinT     = moutT  + 131072;               // [256][1024]
  _Float16*  p1T      = pinT   + 262144;               // [512][256]
  _Float16*  p2T      = p1T    + 131072;               // [256][512]
  _Float16*  wbT      = p2T    + 131072;               // [1024][1024]
  _Float16*  bank_h   = wbT    + 1048576;              // [64][256]
  _Float16*  bankT_h  = bank_h + 16384;                // [256][64]
  float4*    mlthr    = (float4*)(bankT_h + 16384);    // [2][4096] {m,l,thr}

  const dim3 blk(256);
  const float scale = 0.0625f;
  const long QZ  = (long)4096 * 768;
  const long VZ  = (long)256 * 4096;
  const long SZH = (long)4096 * 4096;

  // ---- casts / weight transposes ----
  cast_xh<<<dim3(2048), blk, 0, stream>>>(x, x_h, 1048576);
  cast_xh<<<dim3(8), blk, 0, stream>>>(memory_bank, bank_h, 2048);
  transpose_cast_w<<<dim3(24,32), blk, 0, stream>>>(local_qkv_w,  1024,  768, lqkvT);
  transpose_cast_w<<<dim3(24,32), blk, 0, stream>>>(sparse_qkv_w, 1024,  768, sqkvT);
  transpose_cast_w<<<dim3( 8,32), blk, 0, stream>>>(memory_proj_w,1024,  256, mprojT);
  transpose_cast_w<<<dim3( 8,16), blk, 0, stream>>>(mem_out_w,     512,  256, moutT);
  transpose_cast_w<<<dim3( 8,32), blk, 0, stream>>>(pred_in_w,    1024,  256, pinT);
  transpose_cast_w<<<dim3(16, 8), blk, 0, stream>>>(pred1_w,       256,  512, p1T);
  transpose_cast_w<<<dim3( 8,16), blk, 0, stream>>>(pred2_w,       512,  256, p2T);
  transpose_cast_w<<<dim3(32,32), blk, 0, stream>>>(warboss_w,    1024, 1024, wbT);
  transpose_cast_w<<<dim3( 8, 2), blk, 0, stream>>>(memory_bank,    64,  256, bankT_h);

  // ---- QKV projections (merged z=2: local / sparse) ----
  gemm_ht<128,128,1,0><<<dim3(6,64,2), blk, 0, stream>>>(x_h,0,1024, lqkvT,786432,1024,
                                                         qkv_l,6291456,768, 1024, 1.f, nullptr);

  // ---- memory head (GEMM chain) -> comb[:, 512:768] ----
  gemm_ht<64,64,1,0><<<dim3(4,128), blk, 0, stream>>>(x_h,0,1024, mprojT,0,1024, mem_cat,0,512, 1024, 1.f, nullptr);
  gemm_ht<64,64,0,0><<<dim3(1,128), blk, 0, stream>>>(mem_cat,0,512, bank_h,0,256, (void*)mscore,0,64, 256, 1.f, nullptr);
  msoftmax64<<<dim3(2048), blk, 0, stream>>>(mscore, mprob);
  gemm_ht<64,64,1,0><<<dim3(4,128), blk, 0, stream>>>(mprob,0,64, bankT_h,0,64, mem_cat+256,0,512, 64, 1.f, nullptr);
  gemm_ht<64,64,1,0><<<dim3(4,128), blk, 0, stream>>>(mem_cat,0,512, moutT,0,512, comb+512,0,1024, 512, 1.f, mem_out_b);

  // ---- prediction head -> comb[:, 768:1024] ----
  gemm_ht<64,64,1,0><<<dim3(4,128), blk, 0, stream>>>(x_h,0,1024, pinT,0,1024, h_in,0,256, 1024, 1.f, pred_in_b);
  gemm_ht<64,128,1,1><<<dim3(4,128), blk, 0, stream>>>(h_in,0,256, p1T,0,256, h1,0,512, 256, 1.f, pred1_b);
  gemm_ht<64,64,1,0><<<dim3(4,128), blk, 0, stream>>>(h1,0,512, p2T,0,512, comb+768,0,1024, 512, 1.f, pred2_b);

  // ---- local (full) attention -> comb[:, 0:256] ----
  transpose_h<<<dim3(8,128,2), blk, 0, stream>>>(qkv_l+512, QZ, 768, Vt, VZ, 4096);
  gemm_ht<128,128,1,0><<<dim3(32,32,2), blk, 0, stream>>>(qkv_l,QZ,768, qkv_l+256,QZ,768,
                                                          (void*)scores_h,SZH,4096, 256, scale, nullptr);
  rowstat_local<<<dim3(8192), blk, 0, stream>>>(scores_h, mlthr);
  gemm_pv_exp<64,256,0><<<dim3(1,64,16), blk, 0, stream>>>(scores_h,SZH,4096, Vt,VZ,4096, mlthr, Ph, 8, 512);
  reduce8h<<<dim3(2048), blk, 0, stream>>>(Ph, mlthr, comb, 0, 524288);

  // ---- sparse (top-k) attention -> comb[:, 256:512] ----
  transpose_h<<<dim3(8,128,2), blk, 0, stream>>>(qkv_s+512, QZ, 768, Vt, VZ, 4096);
  gemm_ht<128,128,1,0><<<dim3(32,32,2), blk, 0, stream>>>(qkv_s,QZ,768, qkv_s+256,QZ,768,
                                                          (void*)scores_h,SZH,4096, 256, scale, nullptr);
  rowstat_sparse<<<dim3(8192), blk, 0, stream>>>(scores_h, mlthr, 409);
  gemm_pv_exp<64,256,1><<<dim3(1,64,16), blk, 0, stream>>>(scores_h,SZH,4096, Vt,VZ,4096, mlthr, Ph, 8, 512);
  reduce8h<<<dim3(2048), blk, 0, stream>>>(Ph, mlthr, comb, 256, 524288);

  // ---- output projection (f32 out; overwrites the Ph scratch region) ----
  gemm_ht<128,128,0,0><<<dim3(8,64), blk, 0, stream>>>(comb,0,1024, wbT,0,1024, (void*)out,0,1024, 1024, 1.f, warboss_b);
}

// Round 16
// 396.604 us; speedup vs baseline: 1.0812x; 1.0052x over previous
//
#include <hip/hip_runtime.h>
#include <hip/hip_bf16.h>
#include <hip/hip_fp16.h>

typedef __attribute__((ext_vector_type(8))) _Float16 half8;
typedef __attribute__((ext_vector_type(4))) _Float16 half4v;
typedef __attribute__((ext_vector_type(4))) float f32x4;

__device__ __forceinline__ float wred_max(float v){
  #pragma unroll
  for (int o = 32; o; o >>= 1) v = fmaxf(v, __shfl_xor(v, o));
  return v;
}
__device__ __forceinline__ float wred_sum(float v){
  #pragma unroll
  for (int o = 32; o; o >>= 1) v += __shfl_xor(v, o);
  return v;
}
__device__ __forceinline__ unsigned short h2u(_Float16 h){
  unsigned short u;
  __builtin_memcpy(&u, &h, 2);
  return u;
}
__device__ __forceinline__ float u2hf(unsigned short u){
  _Float16 h;
  __builtin_memcpy(&h, &u, 2);
  return (float)h;
}
__device__ __forceinline__ _Float16 hexp16(_Float16 d){
  __half hd, he;
  __builtin_memcpy(&hd, &d, 2);
  he = hexp(hd);
  _Float16 r;
  __builtin_memcpy(&r, &he, 2);
  return r;
}

// T1: bijective XCD-aware block remap (chunked); identity when nwg % 8 != 0.
__device__ __forceinline__ void xcd_swz(int &bx, int &by, int &bz){
  const int gx = gridDim.x, gy = gridDim.y, gz = gridDim.z;
  const long nwg = (long)gx * gy * gz;
  if ((nwg & 7) != 0) return;
  long flat = bx + (long)gx * (by + (long)gy * bz);
  const long cpx = nwg >> 3;
  flat = (flat & 7) * cpx + (flat >> 3);
  bx = (int)(flat % gx); flat /= gx;
  by = (int)(flat % gy);
  bz = (int)(flat / gy);
}

#define GLOAD16(GP, LP) __builtin_amdgcn_global_load_lds( \
    (const __attribute__((address_space(1))) void*)(GP),  \
    (__attribute__((address_space(3))) void*)(LP), 16, 0, 0)

// ======== MFMA GEMM, 2-phase double-buffered: C = alpha * A @ B^T (+bias) ========
template<int BM, int BN, int OUT_F16, int ACT>
__global__ __launch_bounds__(256) void gemm_ht(
    const _Float16* __restrict__ A, long saz, int lda,
    const _Float16* __restrict__ B, long sbz, int ldb,
    void* __restrict__ Cv, long scz, int ldc,
    int K, float alpha, const float* __restrict__ bias)
{
  constexpr int FM = BM / 32, FN = BN / 32;
  __shared__ __align__(16) _Float16 Asl[2][BM * 32];
  __shared__ __align__(16) _Float16 Bsl[2][BN * 32];
  const int t = threadIdx.x;
  const int wid = t >> 6, lane = t & 63;
  const int wr = wid >> 1, wc = wid & 1;
  const int lr = lane & 15, kg = lane >> 4;
  int bx = blockIdx.x, by = blockIdx.y, bz = blockIdx.z;
  xcd_swz(bx, by, bz);
  A += (long)bz * saz;
  B += (long)bz * sbz;
  const long row0 = (long)by * BM;
  const long col0 = (long)bx * BN;

  const int arow_t = t >> 2, acol_t = (t & 3) * 8;

  auto stage = [&](int buf, int k0){
    #pragma unroll
    for (int r = 0; r < BM / 64; r++){
      const _Float16* gp = A + (row0 + r*64 + arow_t) * (long)lda + k0 + acol_t;
      GLOAD16(gp, (char*)Asl[buf] + r*4096 + wid*1024);
    }
    #pragma unroll
    for (int r = 0; r < BN / 64; r++){
      const _Float16* gp = B + (col0 + r*64 + arow_t) * (long)ldb + k0 + acol_t;
      GLOAD16(gp, (char*)Bsl[buf] + r*4096 + wid*1024);
    }
  };

  f32x4 acc[FM][FN];
  #pragma unroll
  for (int i = 0; i < FM; i++)
    #pragma unroll
    for (int j = 0; j < FN; j++)
      acc[i][j] = (f32x4){0.f, 0.f, 0.f, 0.f};

  stage(0, 0);
  __syncthreads();
  int cur = 0;
  for (int k0 = 0; k0 < K; k0 += 32){
    if (k0 + 32 < K) stage(cur ^ 1, k0 + 32);
    half8 af[FM], bfv[FN];
    #pragma unroll
    for (int i = 0; i < FM; i++)
      af[i] = *(const half8*)((const char*)Asl[cur] + (wr*(BM/2) + i*16 + lr)*64 + kg*16);
    #pragma unroll
    for (int j = 0; j < FN; j++)
      bfv[j] = *(const half8*)((const char*)Bsl[cur] + (wc*(BN/2) + j*16 + lr)*64 + kg*16);
    #pragma unroll
    for (int i = 0; i < FM; i++)
      #pragma unroll
      for (int j = 0; j < FN; j++)
        acc[i][j] = __builtin_amdgcn_mfma_f32_16x16x32_f16(af[i], bfv[j], acc[i][j], 0, 0, 0);
    __syncthreads();
    cur ^= 1;
  }

  _Float16* Ch = (_Float16*)Cv + (long)bz * scz;
  float*    Cf = (float*)Cv    + (long)bz * scz;
  #pragma unroll
  for (int i = 0; i < FM; i++){
    #pragma unroll
    for (int j = 0; j < FN; j++){
      #pragma unroll
      for (int q = 0; q < 4; q++){
        long rr = row0 + wr*(BM/2) + i*16 + kg*4 + q;
        long cc = col0 + wc*(BN/2) + j*16 + lr;
        float val = acc[i][j][q] * alpha;
        if (bias) val += bias[cc];
        if constexpr (ACT) val = 0.5f * val * (1.0f + erff(val * 0.70710678118654752f));
        if constexpr (OUT_F16) Ch[rr*(long)ldc + cc] = (_Float16)val;
        else                   Cf[rr*(long)ldc + cc] = val;
      }
    }
  }
}

// ======== PV GEMM, 2-phase dbuf, fused f16-exp/mask on A (reg-staged, write-late) ========
template<int BM, int BN, int SPARSE>
__global__ __launch_bounds__(256) void gemm_pv_exp(
    const _Float16* __restrict__ A, long saz, int lda,
    const _Float16* __restrict__ B, long sbz, int ldb,
    const float4* __restrict__ mlthr,
    _Float16* __restrict__ Ph, int nsplit, int Ksplit)
{
  constexpr int FM = BM / 32, FN = BN / 32;
  __shared__ __align__(16) _Float16 Asl[2][BM * 32];
  __shared__ __align__(16) _Float16 Bsl[2][BN * 32];
  const int t = threadIdx.x;
  const int wid = t >> 6, lane = t & 63;
  const int wr = wid >> 1, wc = wid & 1;
  const int lr = lane & 15, kg = lane >> 4;
  int bx = blockIdx.x, by = blockIdx.y, bz = blockIdx.z;
  xcd_swz(bx, by, bz);
  const int z = bz, batch = z / nsplit, split = z % nsplit;
  A += (long)batch * saz;
  B += (long)batch * sbz;
  _Float16* Pz = Ph + (size_t)z * (4096 * 256);
  const long row0 = (long)by * BM;
  const int Kbase = split * Ksplit;

  const long arow = row0 + (t >> 2);
  const float4 mt = mlthr[(long)batch*4096 + arow];
  const _Float16 mh  = (_Float16)mt.x;
  const _Float16 thh = (_Float16)mt.z;   // thr is an exact f16 value (or -inf for local)
  const _Float16* Ap = A + arow * (long)lda + Kbase + (t & 3) * 8;

  const int arow_t = t >> 2, acol_t = (t & 3) * 8;

  auto stageB = [&](int buf, int k0){
    #pragma unroll
    for (int r = 0; r < BN / 64; r++){
      const _Float16* gp = B + (r*64 + arow_t) * (long)ldb + Kbase + k0 + acol_t;
      GLOAD16(gp, (char*)Bsl[buf] + r*4096 + wid*1024);
    }
  };
  auto expw = [&](int buf, half8 ld){
    half8 st;
    #pragma unroll
    for (int e = 0; e < 8; e++){
      _Float16 ev = hexp16(ld[e] - mh);
      if constexpr (SPARSE) st[e] = (ld[e] >= thh) ? ev : (_Float16)0.f;
      else                  st[e] = ev;
    }
    *(half8*)((char*)Asl[buf] + t*16) = st;
  };

  f32x4 acc[FM][FN];
  #pragma unroll
  for (int i = 0; i < FM; i++)
    #pragma unroll
    for (int j = 0; j < FN; j++)
      acc[i][j] = (f32x4){0.f, 0.f, 0.f, 0.f};

  stageB(0, 0);
  expw(0, *(const half8*)(Ap + 0));
  __syncthreads();
  int cur = 0;
  for (int k0 = 0; k0 < Ksplit; k0 += 32){
    const bool more = (k0 + 32 < Ksplit);
    half8 lda_next;
    if (more){
      stageB(cur ^ 1, k0 + 32);
      lda_next = *(const half8*)(Ap + k0 + 32);
    }
    half8 af[FM], bfv[FN];
    #pragma unroll
    for (int i = 0; i < FM; i++)
      af[i] = *(const half8*)((const char*)Asl[cur] + (wr*(BM/2) + i*16 + lr)*64 + kg*16);
    #pragma unroll
    for (int j = 0; j < FN; j++)
      bfv[j] = *(const half8*)((const char*)Bsl[cur] + (wc*(BN/2) + j*16 + lr)*64 + kg*16);
    #pragma unroll
    for (int i = 0; i < FM; i++)
      #pragma unroll
      for (int j = 0; j < FN; j++)
        acc[i][j] = __builtin_amdgcn_mfma_f32_16x16x32_f16(af[i], bfv[j], acc[i][j], 0, 0, 0);
    if (more) expw(cur ^ 1, lda_next);
    __syncthreads();
    cur ^= 1;
  }

  #pragma unroll
  for (int i = 0; i < FM; i++)
    #pragma unroll
    for (int j = 0; j < FN; j++)
      #pragma unroll
      for (int q = 0; q < 4; q++){
        long rr = row0 + wr*(BM/2) + i*16 + kg*4 + q;
        long cc = wc*(BN/2) + j*16 + lr;
        Pz[rr*256 + cc] = (_Float16)acc[i][j][q];
      }
}

// ======== sum 8 f16 partials, divide by l -> f16 comb at column offset ========
__global__ __launch_bounds__(256) void reduce8h(const _Float16* __restrict__ Ph,
                                                const float4* __restrict__ mlthr,
                                                _Float16* __restrict__ dst, int coff, int nq){
  int i = blockIdx.x * 256 + threadIdx.x;
  if (i >= nq) return;
  int b = i >> 18;
  int r = i & 262143;
  int row = r >> 6, col4 = r & 63;
  float sx = 0.f, sy = 0.f, sz = 0.f, sw = 0.f;
  #pragma unroll
  for (int sp = 0; sp < 8; sp++){
    half4v p = *(const half4v*)(Ph + (((size_t)(b*8 + sp)*4096 + row)*256 + col4*4));
    sx += (float)p[0]; sy += (float)p[1]; sz += (float)p[2]; sw += (float)p[3];
  }
  const float inv = 1.0f / mlthr[(long)b*4096 + row].y;
  half4v o;
  o[0] = (_Float16)(sx*inv); o[1] = (_Float16)(sy*inv);
  o[2] = (_Float16)(sz*inv); o[3] = (_Float16)(sw*inv);
  *(half4v*)(dst + ((size_t)b*4096 + row)*1024 + coff + col4*4) = o;
}

// ======== cast f32 -> f16 (8 elems/thread) ========
__global__ __launch_bounds__(256) void cast_xh(const float* __restrict__ in,
                                               _Float16* __restrict__ out, int n8){
  int i = blockIdx.x * 256 + threadIdx.x;
  const int stride = gridDim.x * 256;
  for (; i < n8; i += stride){
    float4 a = ((const float4*)in)[2*i];
    float4 b = ((const float4*)in)[2*i + 1];
    half8 o;
    o[0]=(_Float16)a.x; o[1]=(_Float16)a.y; o[2]=(_Float16)a.z; o[3]=(_Float16)a.w;
    o[4]=(_Float16)b.x; o[5]=(_Float16)b.y; o[6]=(_Float16)b.z; o[7]=(_Float16)b.w;
    *(half8*)(out + (size_t)i*8) = o;
  }
}

// ======== transpose+cast weight: in (R x C) f32 -> out (C x R) f16 ========
__global__ __launch_bounds__(256) void transpose_cast_w(const float* __restrict__ in, int R, int C,
                                                        _Float16* __restrict__ out){
  __shared__ float tile[32][33];
  const int c0 = blockIdx.x * 32, r0 = blockIdx.y * 32;
  const int tx = threadIdx.x & 31, ty = threadIdx.x >> 5;
  #pragma unroll
  for (int i = 0; i < 32; i += 8)
    tile[ty+i][tx] = in[(size_t)(r0+ty+i)*C + c0+tx];
  __syncthreads();
  #pragma unroll
  for (int i = 0; i < 32; i += 8)
    out[(size_t)(c0+ty+i)*R + r0+tx] = (_Float16)tile[tx][ty+i];
}

// ======== f16 transpose: in (R x C, ld_in) -> out (C x R, ld_out), z-batched ========
__global__ __launch_bounds__(256) void transpose_h(
    const _Float16* __restrict__ in, long in_z, int ld_in,
    _Float16* __restrict__ out, long out_z, int ld_out)
{
  __shared__ _Float16 tile[32][34];
  const _Float16* ip = in + (long)blockIdx.z * in_z;
  _Float16* op = out + (long)blockIdx.z * out_z;
  const int c0 = blockIdx.x * 32, r0 = blockIdx.y * 32;
  const int tx = threadIdx.x & 31, ty = threadIdx.x >> 5;
  #pragma unroll
  for (int i = 0; i < 32; i += 8)
    tile[ty+i][tx] = ip[(long)(r0+ty+i)*ld_in + c0+tx];
  __syncthreads();
  #pragma unroll
  for (int i = 0; i < 32; i += 8)
    op[(long)(c0+ty+i)*ld_out + r0+tx] = tile[tx][ty+i];
}

// ======== rowstat (local): m = rowmax, l = sum exp(v-m); read-only ========
__global__ __launch_bounds__(256) void rowstat_local(const _Float16* __restrict__ sc,
                                                     float4* __restrict__ mlthr){
  __shared__ float red[4], red2[4];
  const int t = threadIdx.x, lane = t & 63, wid = t >> 6;
  const _Float16* p = sc + (size_t)blockIdx.x * 4096;
  half8 a = ((const half8*)p)[t*2];
  half8 b = ((const half8*)p)[t*2 + 1];
  float v[16];
  #pragma unroll
  for (int e = 0; e < 8; e++){ v[e] = (float)a[e]; v[8+e] = (float)b[e]; }
  float m = v[0];
  #pragma unroll
  for (int e = 1; e < 16; e++) m = fmaxf(m, v[e]);
  m = wred_max(m);
  if (lane == 0) red[wid] = m;
  __syncthreads();
  m = fmaxf(fmaxf(red[0], red[1]), fmaxf(red[2], red[3]));
  float s = 0.f;
  #pragma unroll
  for (int e = 0; e < 16; e++) s += __expf(v[e] - m);
  s = wred_sum(s);
  if (lane == 0) red2[wid] = s;
  __syncthreads();
  if (t == 0){
    s = red2[0] + red2[1] + red2[2] + red2[3];
    mlthr[blockIdx.x] = make_float4(m, s, -60000.0f, 0.f);
  }
}

// ======== rowstat (sparse): exact top-k threshold (2x8-bit radix on u16 keys) ========
__global__ __launch_bounds__(256) void rowstat_sparse(const _Float16* __restrict__ sc,
                                                      float4* __restrict__ mlthr, int ksel){
  __shared__ unsigned hist4[4][256];
  __shared__ unsigned hrev[256];
  __shared__ unsigned suf[257];
  __shared__ unsigned wtot[4];
  __shared__ int selb;
  __shared__ float red[4], red2[4];
  const int t = threadIdx.x, lane = t & 63, wid = t >> 6;
  const _Float16* p = sc + (size_t)blockIdx.x * 4096;
  half8 a = ((const half8*)p)[t*2];
  half8 b = ((const half8*)p)[t*2 + 1];
  float v[16]; unsigned kk[16];
  #pragma unroll
  for (int e = 0; e < 8; e++){
    unsigned short u0 = h2u(a[e]);
    unsigned short u1 = h2u(b[e]);
    kk[e]   = (u0 & 0x8000u) ? (unsigned)(unsigned short)~u0 : (unsigned)(u0 | 0x8000u);
    kk[8+e] = (u1 & 0x8000u) ? (unsigned)(unsigned short)~u1 : (unsigned)(u1 | 0x8000u);
    v[e] = (float)a[e]; v[8+e] = (float)b[e];
  }
  float m = v[0];
  #pragma unroll
  for (int e = 1; e < 16; e++) m = fmaxf(m, v[e]);
  m = wred_max(m);
  if (lane == 0) red[wid] = m;
  __syncthreads();
  m = fmaxf(fmaxf(red[0], red[1]), fmaxf(red[2], red[3]));

  // ---- pass 1: high byte ----
  ((uint4*)hist4)[t] = (uint4){0u,0u,0u,0u};
  __syncthreads();
  #pragma unroll
  for (int e = 0; e < 16; e++) atomicAdd(&hist4[wid][kk[e] >> 8], 1u);
  __syncthreads();
  hrev[t] = hist4[0][t] + hist4[1][t] + hist4[2][t] + hist4[3][t];
  __syncthreads();
  unsigned x = hrev[255 - t];
  #pragma unroll
  for (int o = 1; o < 64; o <<= 1){
    unsigned y = __shfl_up(x, o);
    if (lane >= o) x += y;
  }
  if (lane == 63) wtot[wid] = x;
  __syncthreads();
  #pragma unroll
  for (int w = 0; w < 4; w++) if (w < wid) x += wtot[w];
  suf[255 - t] = x;
  if (t == 0) suf[256] = 0u;
  __syncthreads();
  const unsigned ku = (unsigned)ksel;
  if (suf[t] >= ku && suf[t+1] < ku) selb = t;
  __syncthreads();
  const int b1 = selb;
  const unsigned rem = ku - suf[b1+1];
  __syncthreads();

  // ---- pass 2: low byte among high==b1 ----
  ((uint4*)hist4)[t] = (uint4){0u,0u,0u,0u};
  __syncthreads();
  #pragma unroll
  for (int e = 0; e < 16; e++)
    if ((int)(kk[e] >> 8) == b1) atomicAdd(&hist4[wid][kk[e] & 255u], 1u);
  __syncthreads();
  hrev[t] = hist4[0][t] + hist4[1][t] + hist4[2][t] + hist4[3][t];
  __syncthreads();
  x = hrev[255 - t];
  #pragma unroll
  for (int o = 1; o < 64; o <<= 1){
    unsigned y = __shfl_up(x, o);
    if (lane >= o) x += y;
  }
  if (lane == 63) wtot[wid] = x;
  __syncthreads();
  #pragma unroll
  for (int w = 0; w < 4; w++) if (w < wid) x += wtot[w];
  suf[255 - t] = x;
  if (t == 0) suf[256] = 0u;
  __syncthreads();
  if (suf[t] >= rem && suf[t+1] < rem) selb = t;
  __syncthreads();
  const unsigned Tkey = ((unsigned)b1 << 8) | (unsigned)selb;
  const unsigned short tu = (Tkey & 0x8000u) ? (unsigned short)(Tkey & 0x7fffu)
                                             : (unsigned short)~Tkey;
  const float thr = u2hf(tu);

  float s = 0.f;
  #pragma unroll
  for (int e = 0; e < 16; e++)
    s += (v[e] >= thr) ? __expf(v[e] - m) : 0.f;
  s = wred_sum(s);
  if (lane == 0) red2[wid] = s;
  __syncthreads();
  if (t == 0){
    s = red2[0] + red2[1] + red2[2] + red2[3];
    mlthr[blockIdx.x] = make_float4(m, s, thr, 0.f);
  }
}

// ======== memory-head softmax over 64 scores: one wave per row ========
__global__ __launch_bounds__(256) void msoftmax64(const float* __restrict__ mscore,
                                                  _Float16* __restrict__ mprob){
  const int t = threadIdx.x, lane = t & 63, wid = t >> 6;
  const size_t row = (size_t)blockIdx.x * 4 + wid;
  float v = mscore[row*64 + lane];
  float m = wred_max(v);
  float e = expf(v - m);
  float s = wred_sum(e);
  mprob[row*64 + lane] = (_Float16)(e / s);
}

extern "C" void kernel_launch(void* const* d_in, const int* in_sizes, int n_in,
                              void* d_out, int out_size, void* d_ws, size_t ws_size,
                              hipStream_t stream)
{
  const float* x             = (const float*)d_in[0];
  const float* local_qkv_w   = (const float*)d_in[1];
  const float* sparse_qkv_w  = (const float*)d_in[2];
  const float* memory_bank   = (const float*)d_in[3];
  const float* memory_proj_w = (const float*)d_in[4];
  const float* mem_out_w     = (const float*)d_in[5];
  const float* mem_out_b     = (const float*)d_in[6];
  const float* pred_in_w     = (const float*)d_in[7];
  const float* pred_in_b     = (const float*)d_in[8];
  const float* pred1_w       = (const float*)d_in[9];
  const float* pred1_b       = (const float*)d_in[10];
  const float* pred2_w       = (const float*)d_in[11];
  const float* pred2_b       = (const float*)d_in[12];
  const float* warboss_w     = (const float*)d_in[13];
  const float* warboss_b     = (const float*)d_in[14];
  float* out = (float*)d_out;
  _Float16* Ph = (_Float16*)d_out;   // f16 PV partials [16][4096][256] = 33.5MB = d_out

  char* wsb = (char*)d_ws;
  _Float16*  scores_h = (_Float16*)wsb;                // [2][4096][4096] f16 (67MB)
  _Float16*  x_h      = (_Float16*)wsb;
  _Float16*  mem_cat  = (_Float16*)(wsb + 16777216);
  _Float16*  h_in     = (_Float16*)(wsb + 25165824);
  _Float16*  h1       = (_Float16*)(wsb + 29360128);
  float*     mscore   = (float*)(wsb + 37748736);
  _Float16*  mprob    = (_Float16*)(wsb + 39845888);
  _Float16*  qkv_l    = (_Float16*)(wsb + 67108864);   // [8192][768]
  _Float16*  qkv_s    = (_Float16*)(wsb + 79691776);   // [8192][768]
  _Float16*  Vt       = (_Float16*)(wsb + 92274688);   // [2][256][4096]
  _Float16*  comb     = (_Float16*)(wsb + 96468992);   // [8192][1024]
  _Float16*  lqkvT    = (_Float16*)(wsb + 113246208);  // [768][1024]
  _Float16*  sqkvT    = lqkvT  + 786432;
  _Float16*  mprojT   = sqkvT  + 786432;               // [256][1024]
  _Float16*  moutT    = mprojT + 262144;               // [256][512]
  _Float16*  pinT     = moutT  + 131072;               // [256][1024]
  _Float16*  p1T      = pinT   + 262144;               // [512][256]
  _Float16*  p2T      = p1T    + 131072;               // [256][512]
  _Float16*  wbT      = p2T    + 131072;               // [1024][1024]
  _Float16*  bank_h   = wbT    + 1048576;              // [64][256]
  _Float16*  bankT_h  = bank_h + 16384;                // [256][64]
  float4*    mlthr    = (float4*)(bankT_h + 16384);    // [2][4096] {m,l,thr}

  const dim3 blk(256);
  const float scale = 0.0625f;
  const long QZ  = (long)4096 * 768;
  const long VZ  = (long)256 * 4096;
  const long SZH = (long)4096 * 4096;

  // ---- casts / weight transposes ----
  cast_xh<<<dim3(2048), blk, 0, stream>>>(x, x_h, 1048576);
  cast_xh<<<dim3(8), blk, 0, stream>>>(memory_bank, bank_h, 2048);
  transpose_cast_w<<<dim3(24,32), blk, 0, stream>>>(local_qkv_w,  1024,  768, lqkvT);
  transpose_cast_w<<<dim3(24,32), blk, 0, stream>>>(sparse_qkv_w, 1024,  768, sqkvT);
  transpose_cast_w<<<dim3( 8,32), blk, 0, stream>>>(memory_proj_w,1024,  256, mprojT);
  transpose_cast_w<<<dim3( 8,16), blk, 0, stream>>>(mem_out_w,     512,  256, moutT);
  transpose_cast_w<<<dim3( 8,32), blk, 0, stream>>>(pred_in_w,    1024,  256, pinT);
  transpose_cast_w<<<dim3(16, 8), blk, 0, stream>>>(pred1_w,       256,  512, p1T);
  transpose_cast_w<<<dim3( 8,16), blk, 0, stream>>>(pred2_w,       512,  256, p2T);
  transpose_cast_w<<<dim3(32,32), blk, 0, stream>>>(warboss_w,    1024, 1024, wbT);
  transpose_cast_w<<<dim3( 8, 2), blk, 0, stream>>>(memory_bank,    64,  256, bankT_h);

  // ---- QKV projections (merged z=2: local / sparse) ----
  gemm_ht<128,128,1,0><<<dim3(6,64,2), blk, 0, stream>>>(x_h,0,1024, lqkvT,786432,1024,
                                                         qkv_l,6291456,768, 1024, 1.f, nullptr);

  // ---- memory head (GEMM chain) -> comb[:, 512:768] ----
  gemm_ht<64,64,1,0><<<dim3(4,128), blk, 0, stream>>>(x_h,0,1024, mprojT,0,1024, mem_cat,0,512, 1024, 1.f, nullptr);
  gemm_ht<64,64,0,0><<<dim3(1,128), blk, 0, stream>>>(mem_cat,0,512, bank_h,0,256, (void*)mscore,0,64, 256, 1.f, nullptr);
  msoftmax64<<<dim3(2048), blk, 0, stream>>>(mscore, mprob);
  gemm_ht<64,64,1,0><<<dim3(4,128), blk, 0, stream>>>(mprob,0,64, bankT_h,0,64, mem_cat+256,0,512, 64, 1.f, nullptr);
  gemm_ht<64,64,1,0><<<dim3(4,128), blk, 0, stream>>>(mem_cat,0,512, moutT,0,512, comb+512,0,1024, 512, 1.f, mem_out_b);

  // ---- prediction head -> comb[:, 768:1024] ----
  gemm_ht<64,64,1,0><<<dim3(4,128), blk, 0, stream>>>(x_h,0,1024, pinT,0,1024, h_in,0,256, 1024, 1.f, pred_in_b);
  gemm_ht<64,128,1,1><<<dim3(4,128), blk, 0, stream>>>(h_in,0,256, p1T,0,256, h1,0,512, 256, 1.f, pred1_b);
  gemm_ht<64,64,1,0><<<dim3(4,128), blk, 0, stream>>>(h1,0,512, p2T,0,512, comb+768,0,1024, 512, 1.f, pred2_b);

  // ---- local (full) attention -> comb[:, 0:256] ----
  transpose_h<<<dim3(8,128,2), blk, 0, stream>>>(qkv_l+512, QZ, 768, Vt, VZ, 4096);
  gemm_ht<128,128,1,0><<<dim3(32,32,2), blk, 0, stream>>>(qkv_l,QZ,768, qkv_l+256,QZ,768,
                                                          (void*)scores_h,SZH,4096, 256, scale, nullptr);
  rowstat_local<<<dim3(8192), blk, 0, stream>>>(scores_h, mlthr);
  gemm_pv_exp<64,256,0><<<dim3(1,64,16), blk, 0, stream>>>(scores_h,SZH,4096, Vt,VZ,4096, mlthr, Ph, 8, 512);
  reduce8h<<<dim3(2048), blk, 0, stream>>>(Ph, mlthr, comb, 0, 524288);

  // ---- sparse (top-k) attention -> comb[:, 256:512] ----
  transpose_h<<<dim3(8,128,2), blk, 0, stream>>>(qkv_s+512, QZ, 768, Vt, VZ, 4096);
  gemm_ht<128,128,1,0><<<dim3(32,32,2), blk, 0, stream>>>(qkv_s,QZ,768, qkv_s+256,QZ,768,
                                                          (void*)scores_h,SZH,4096, 256, scale, nullptr);
  rowstat_sparse<<<dim3(8192), blk, 0, stream>>>(scores_h, mlthr, 409);
  gemm_pv_exp<64,256,1><<<dim3(1,64,16), blk, 0, stream>>>(scores_h,SZH,4096, Vt,VZ,4096, mlthr, Ph, 8, 512);
  reduce8h<<<dim3(2048), blk, 0, stream>>>(Ph, mlthr, comb, 256, 524288);

  // ---- output projection (f32 out; overwrites the Ph scratch region) ----
  gemm_ht<128,128,0,0><<<dim3(8,64), blk, 0, stream>>>(comb,0,1024, wbT,0,1024, (void*)out,0,1024, 1024, 1.f, warboss_b);
}

// Round 17
// 382.005 us; speedup vs baseline: 1.1225x; 1.0382x over previous
//
#include <hip/hip_runtime.h>
#include <hip/hip_bf16.h>
#include <hip/hip_fp16.h>

typedef __attribute__((ext_vector_type(8))) _Float16 half8;
typedef __attribute__((ext_vector_type(4))) _Float16 half4v;
typedef __attribute__((ext_vector_type(4))) float f32x4;

__device__ __forceinline__ float wred_max(float v){
  #pragma unroll
  for (int o = 32; o; o >>= 1) v = fmaxf(v, __shfl_xor(v, o));
  return v;
}
__device__ __forceinline__ float wred_sum(float v){
  #pragma unroll
  for (int o = 32; o; o >>= 1) v += __shfl_xor(v, o);
  return v;
}
__device__ __forceinline__ unsigned short h2u(_Float16 h){
  unsigned short u;
  __builtin_memcpy(&u, &h, 2);
  return u;
}
__device__ __forceinline__ float u2hf(unsigned short u){
  _Float16 h;
  __builtin_memcpy(&h, &u, 2);
  return (float)h;
}
__device__ __forceinline__ _Float16 hexp16(_Float16 d){
  __half hd, he;
  __builtin_memcpy(&hd, &d, 2);
  he = hexp(hd);
  _Float16 r;
  __builtin_memcpy(&r, &he, 2);
  return r;
}

// T1: bijective XCD-aware block remap (chunked); identity when nwg % 8 != 0.
__device__ __forceinline__ void xcd_swz(int &bx, int &by, int &bz){
  const int gx = gridDim.x, gy = gridDim.y, gz = gridDim.z;
  const long nwg = (long)gx * gy * gz;
  if ((nwg & 7) != 0) return;
  long flat = bx + (long)gx * (by + (long)gy * bz);
  const long cpx = nwg >> 3;
  flat = (flat & 7) * cpx + (flat >> 3);
  bx = (int)(flat % gx); flat /= gx;
  by = (int)(flat % gy);
  bz = (int)(flat / gy);
}

#define GLOAD16(GP, LP) __builtin_amdgcn_global_load_lds( \
    (const __attribute__((address_space(1))) void*)(GP),  \
    (__attribute__((address_space(3))) void*)(LP), 16, 0, 0)

// ======== MFMA GEMM, 2-phase double-buffered: C = alpha * A @ B^T (+bias) ========
template<int BM, int BN, int OUT_F16, int ACT>
__global__ __launch_bounds__(256) void gemm_ht(
    const _Float16* __restrict__ A, long saz, int lda,
    const _Float16* __restrict__ B, long sbz, int ldb,
    void* __restrict__ Cv, long scz, int ldc,
    int K, float alpha, const float* __restrict__ bias)
{
  constexpr int FM = BM / 32, FN = BN / 32;
  __shared__ __align__(16) _Float16 Asl[2][BM * 32];
  __shared__ __align__(16) _Float16 Bsl[2][BN * 32];
  const int t = threadIdx.x;
  const int wid = t >> 6, lane = t & 63;
  const int wr = wid >> 1, wc = wid & 1;
  const int lr = lane & 15, kg = lane >> 4;
  int bx = blockIdx.x, by = blockIdx.y, bz = blockIdx.z;
  xcd_swz(bx, by, bz);
  A += (long)bz * saz;
  B += (long)bz * sbz;
  const long row0 = (long)by * BM;
  const long col0 = (long)bx * BN;

  const int arow_t = t >> 2, acol_t = (t & 3) * 8;

  auto stage = [&](int buf, int k0){
    #pragma unroll
    for (int r = 0; r < BM / 64; r++){
      const _Float16* gp = A + (row0 + r*64 + arow_t) * (long)lda + k0 + acol_t;
      GLOAD16(gp, (char*)Asl[buf] + r*4096 + wid*1024);
    }
    #pragma unroll
    for (int r = 0; r < BN / 64; r++){
      const _Float16* gp = B + (col0 + r*64 + arow_t) * (long)ldb + k0 + acol_t;
      GLOAD16(gp, (char*)Bsl[buf] + r*4096 + wid*1024);
    }
  };

  f32x4 acc[FM][FN];
  #pragma unroll
  for (int i = 0; i < FM; i++)
    #pragma unroll
    for (int j = 0; j < FN; j++)
      acc[i][j] = (f32x4){0.f, 0.f, 0.f, 0.f};

  stage(0, 0);
  __syncthreads();
  int cur = 0;
  for (int k0 = 0; k0 < K; k0 += 32){
    if (k0 + 32 < K) stage(cur ^ 1, k0 + 32);
    half8 af[FM], bfv[FN];
    #pragma unroll
    for (int i = 0; i < FM; i++)
      af[i] = *(const half8*)((const char*)Asl[cur] + (wr*(BM/2) + i*16 + lr)*64 + kg*16);
    #pragma unroll
    for (int j = 0; j < FN; j++)
      bfv[j] = *(const half8*)((const char*)Bsl[cur] + (wc*(BN/2) + j*16 + lr)*64 + kg*16);
    #pragma unroll
    for (int i = 0; i < FM; i++)
      #pragma unroll
      for (int j = 0; j < FN; j++)
        acc[i][j] = __builtin_amdgcn_mfma_f32_16x16x32_f16(af[i], bfv[j], acc[i][j], 0, 0, 0);
    __syncthreads();
    cur ^= 1;
  }

  _Float16* Ch = (_Float16*)Cv + (long)bz * scz;
  float*    Cf = (float*)Cv    + (long)bz * scz;
  #pragma unroll
  for (int i = 0; i < FM; i++){
    #pragma unroll
    for (int j = 0; j < FN; j++){
      #pragma unroll
      for (int q = 0; q < 4; q++){
        long rr = row0 + wr*(BM/2) + i*16 + kg*4 + q;
        long cc = col0 + wc*(BN/2) + j*16 + lr;
        float val = acc[i][j][q] * alpha;
        if (bias) val += bias[cc];
        if constexpr (ACT) val = 0.5f * val * (1.0f + erff(val * 0.70710678118654752f));
        if constexpr (OUT_F16) Ch[rr*(long)ldc + cc] = (_Float16)val;
        else                   Cf[rr*(long)ldc + cc] = val;
      }
    }
  }
}

// ======== PV GEMM, 2-phase dbuf, fused f16-exp/mask on A (reg-staged, write-late) ========
template<int BM, int BN, int SPARSE>
__global__ __launch_bounds__(256) void gemm_pv_exp(
    const _Float16* __restrict__ A, long saz, int lda,
    const _Float16* __restrict__ B, long sbz, int ldb,
    const float4* __restrict__ mlthr,
    _Float16* __restrict__ Ph, int nsplit, int Ksplit)
{
  constexpr int FM = BM / 32, FN = BN / 32;
  __shared__ __align__(16) _Float16 Asl[2][BM * 32];
  __shared__ __align__(16) _Float16 Bsl[2][BN * 32];
  const int t = threadIdx.x;
  const int wid = t >> 6, lane = t & 63;
  const int wr = wid >> 1, wc = wid & 1;
  const int lr = lane & 15, kg = lane >> 4;
  int bx = blockIdx.x, by = blockIdx.y, bz = blockIdx.z;
  xcd_swz(bx, by, bz);
  const int z = bz, batch = z / nsplit, split = z % nsplit;
  A += (long)batch * saz;
  B += (long)batch * sbz;
  _Float16* Pz = Ph + (size_t)z * (4096 * 256);
  const long row0 = (long)by * BM;
  const int Kbase = split * Ksplit;

  const long arow = row0 + (t >> 2);
  const float4 mt = mlthr[(long)batch*4096 + arow];
  const _Float16 mh  = (_Float16)mt.x;
  const _Float16 thh = (_Float16)mt.z;   // thr is an exact f16 value (or -60000 for local)
  const _Float16* Ap = A + arow * (long)lda + Kbase + (t & 3) * 8;

  const int arow_t = t >> 2, acol_t = (t & 3) * 8;

  auto stageB = [&](int buf, int k0){
    #pragma unroll
    for (int r = 0; r < BN / 64; r++){
      const _Float16* gp = B + (r*64 + arow_t) * (long)ldb + Kbase + k0 + acol_t;
      GLOAD16(gp, (char*)Bsl[buf] + r*4096 + wid*1024);
    }
  };
  auto expw = [&](int buf, half8 ld){
    half8 st;
    #pragma unroll
    for (int e = 0; e < 8; e++){
      _Float16 ev = hexp16(ld[e] - mh);
      if constexpr (SPARSE) st[e] = (ld[e] >= thh) ? ev : (_Float16)0.f;
      else                  st[e] = ev;
    }
    *(half8*)((char*)Asl[buf] + t*16) = st;
  };

  f32x4 acc[FM][FN];
  #pragma unroll
  for (int i = 0; i < FM; i++)
    #pragma unroll
    for (int j = 0; j < FN; j++)
      acc[i][j] = (f32x4){0.f, 0.f, 0.f, 0.f};

  stageB(0, 0);
  expw(0, *(const half8*)(Ap + 0));
  __syncthreads();
  int cur = 0;
  for (int k0 = 0; k0 < Ksplit; k0 += 32){
    const bool more = (k0 + 32 < Ksplit);
    half8 lda_next;
    if (more){
      stageB(cur ^ 1, k0 + 32);
      lda_next = *(const half8*)(Ap + k0 + 32);
    }
    half8 af[FM], bfv[FN];
    #pragma unroll
    for (int i = 0; i < FM; i++)
      af[i] = *(const half8*)((const char*)Asl[cur] + (wr*(BM/2) + i*16 + lr)*64 + kg*16);
    #pragma unroll
    for (int j = 0; j < FN; j++)
      bfv[j] = *(const half8*)((const char*)Bsl[cur] + (wc*(BN/2) + j*16 + lr)*64 + kg*16);
    #pragma unroll
    for (int i = 0; i < FM; i++)
      #pragma unroll
      for (int j = 0; j < FN; j++)
        acc[i][j] = __builtin_amdgcn_mfma_f32_16x16x32_f16(af[i], bfv[j], acc[i][j], 0, 0, 0);
    if (more) expw(cur ^ 1, lda_next);
    __syncthreads();
    cur ^= 1;
  }

  #pragma unroll
  for (int i = 0; i < FM; i++)
    #pragma unroll
    for (int j = 0; j < FN; j++)
      #pragma unroll
      for (int q = 0; q < 4; q++){
        long rr = row0 + wr*(BM/2) + i*16 + kg*4 + q;
        long cc = wc*(BN/2) + j*16 + lr;
        Pz[rr*256 + cc] = (_Float16)acc[i][j][q];
      }
}

// ======== sum 4 f16 partials, divide by l -> f16 comb at column offset ========
__global__ __launch_bounds__(256) void reduce4h(const _Float16* __restrict__ Ph,
                                                const float4* __restrict__ mlthr,
                                                _Float16* __restrict__ dst, int coff, int nq){
  int i = blockIdx.x * 256 + threadIdx.x;
  if (i >= nq) return;
  int b = i >> 18;
  int r = i & 262143;
  int row = r >> 6, col4 = r & 63;
  float sx = 0.f, sy = 0.f, sz = 0.f, sw = 0.f;
  #pragma unroll
  for (int sp = 0; sp < 4; sp++){
    half4v p = *(const half4v*)(Ph + (((size_t)(b*4 + sp)*4096 + row)*256 + col4*4));
    sx += (float)p[0]; sy += (float)p[1]; sz += (float)p[2]; sw += (float)p[3];
  }
  const float inv = 1.0f / mlthr[(long)b*4096 + row].y;
  half4v o;
  o[0] = (_Float16)(sx*inv); o[1] = (_Float16)(sy*inv);
  o[2] = (_Float16)(sz*inv); o[3] = (_Float16)(sw*inv);
  *(half4v*)(dst + ((size_t)b*4096 + row)*1024 + coff + col4*4) = o;
}

// ======== cast f32 -> f16 (8 elems/thread) ========
__global__ __launch_bounds__(256) void cast_xh(const float* __restrict__ in,
                                               _Float16* __restrict__ out, int n8){
  int i = blockIdx.x * 256 + threadIdx.x;
  const int stride = gridDim.x * 256;
  for (; i < n8; i += stride){
    float4 a = ((const float4*)in)[2*i];
    float4 b = ((const float4*)in)[2*i + 1];
    half8 o;
    o[0]=(_Float16)a.x; o[1]=(_Float16)a.y; o[2]=(_Float16)a.z; o[3]=(_Float16)a.w;
    o[4]=(_Float16)b.x; o[5]=(_Float16)b.y; o[6]=(_Float16)b.z; o[7]=(_Float16)b.w;
    *(half8*)(out + (size_t)i*8) = o;
  }
}

// ======== transpose+cast weight: in (R x C) f32 -> out (C x R) f16 ========
__global__ __launch_bounds__(256) void transpose_cast_w(const float* __restrict__ in, int R, int C,
                                                        _Float16* __restrict__ out){
  __shared__ float tile[32][33];
  const int c0 = blockIdx.x * 32, r0 = blockIdx.y * 32;
  const int tx = threadIdx.x & 31, ty = threadIdx.x >> 5;
  #pragma unroll
  for (int i = 0; i < 32; i += 8)
    tile[ty+i][tx] = in[(size_t)(r0+ty+i)*C + c0+tx];
  __syncthreads();
  #pragma unroll
  for (int i = 0; i < 32; i += 8)
    out[(size_t)(c0+ty+i)*R + r0+tx] = (_Float16)tile[tx][ty+i];
}

// ======== f16 transpose: in (R x C, ld_in) -> out (C x R, ld_out), z-batched ========
__global__ __launch_bounds__(256) void transpose_h(
    const _Float16* __restrict__ in, long in_z, int ld_in,
    _Float16* __restrict__ out, long out_z, int ld_out)
{
  __shared__ _Float16 tile[32][34];
  const _Float16* ip = in + (long)blockIdx.z * in_z;
  _Float16* op = out + (long)blockIdx.z * out_z;
  const int c0 = blockIdx.x * 32, r0 = blockIdx.y * 32;
  const int tx = threadIdx.x & 31, ty = threadIdx.x >> 5;
  #pragma unroll
  for (int i = 0; i < 32; i += 8)
    tile[ty+i][tx] = ip[(long)(r0+ty+i)*ld_in + c0+tx];
  __syncthreads();
  #pragma unroll
  for (int i = 0; i < 32; i += 8)
    op[(long)(c0+ty+i)*ld_out + r0+tx] = tile[tx][ty+i];
}

// ======== rowstat (local): m = rowmax, l = sum exp(v-m); read-only ========
__global__ __launch_bounds__(256) void rowstat_local(const _Float16* __restrict__ sc,
                                                     float4* __restrict__ mlthr){
  __shared__ float red[4], red2[4];
  const int t = threadIdx.x, lane = t & 63, wid = t >> 6;
  const _Float16* p = sc + (size_t)blockIdx.x * 4096;
  half8 a = ((const half8*)p)[t*2];
  half8 b = ((const half8*)p)[t*2 + 1];
  float v[16];
  #pragma unroll
  for (int e = 0; e < 8; e++){ v[e] = (float)a[e]; v[8+e] = (float)b[e]; }
  float m = v[0];
  #pragma unroll
  for (int e = 1; e < 16; e++) m = fmaxf(m, v[e]);
  m = wred_max(m);
  if (lane == 0) red[wid] = m;
  __syncthreads();
  m = fmaxf(fmaxf(red[0], red[1]), fmaxf(red[2], red[3]));
  float s = 0.f;
  #pragma unroll
  for (int e = 0; e < 16; e++) s += __expf(v[e] - m);
  s = wred_sum(s);
  if (lane == 0) red2[wid] = s;
  __syncthreads();
  if (t == 0){
    s = red2[0] + red2[1] + red2[2] + red2[3];
    mlthr[blockIdx.x] = make_float4(m, s, -60000.0f, 0.f);
  }
}

// ======== rowstat (sparse): exact top-k threshold (2x8-bit radix on u16 keys) ========
__global__ __launch_bounds__(256) void rowstat_sparse(const _Float16* __restrict__ sc,
                                                      float4* __restrict__ mlthr, int ksel){
  __shared__ unsigned hist4[4][256];
  __shared__ unsigned hrev[256];
  __shared__ unsigned suf[257];
  __shared__ unsigned wtot[4];
  __shared__ int selb;
  __shared__ float red[4], red2[4];
  const int t = threadIdx.x, lane = t & 63, wid = t >> 6;
  const _Float16* p = sc + (size_t)blockIdx.x * 4096;
  half8 a = ((const half8*)p)[t*2];
  half8 b = ((const half8*)p)[t*2 + 1];
  float v[16]; unsigned kk[16];
  #pragma unroll
  for (int e = 0; e < 8; e++){
    unsigned short u0 = h2u(a[e]);
    unsigned short u1 = h2u(b[e]);
    kk[e]   = (u0 & 0x8000u) ? (unsigned)(unsigned short)~u0 : (unsigned)(u0 | 0x8000u);
    kk[8+e] = (u1 & 0x8000u) ? (unsigned)(unsigned short)~u1 : (unsigned)(u1 | 0x8000u);
    v[e] = (float)a[e]; v[8+e] = (float)b[e];
  }
  float m = v[0];
  #pragma unroll
  for (int e = 1; e < 16; e++) m = fmaxf(m, v[e]);
  m = wred_max(m);
  if (lane == 0) red[wid] = m;
  __syncthreads();
  m = fmaxf(fmaxf(red[0], red[1]), fmaxf(red[2], red[3]));

  // ---- pass 1: high byte ----
  ((uint4*)hist4)[t] = (uint4){0u,0u,0u,0u};
  __syncthreads();
  #pragma unroll
  for (int e = 0; e < 16; e++) atomicAdd(&hist4[wid][kk[e] >> 8], 1u);
  __syncthreads();
  hrev[t] = hist4[0][t] + hist4[1][t] + hist4[2][t] + hist4[3][t];
  __syncthreads();
  unsigned x = hrev[255 - t];
  #pragma unroll
  for (int o = 1; o < 64; o <<= 1){
    unsigned y = __shfl_up(x, o);
    if (lane >= o) x += y;
  }
  if (lane == 63) wtot[wid] = x;
  __syncthreads();
  #pragma unroll
  for (int w = 0; w < 4; w++) if (w < wid) x += wtot[w];
  suf[255 - t] = x;
  if (t == 0) suf[256] = 0u;
  __syncthreads();
  const unsigned ku = (unsigned)ksel;
  if (suf[t] >= ku && suf[t+1] < ku) selb = t;
  __syncthreads();
  const int b1 = selb;
  const unsigned rem = ku - suf[b1+1];
  __syncthreads();

  // ---- pass 2: low byte among high==b1 ----
  ((uint4*)hist4)[t] = (uint4){0u,0u,0u,0u};
  __syncthreads();
  #pragma unroll
  for (int e = 0; e < 16; e++)
    if ((int)(kk[e] >> 8) == b1) atomicAdd(&hist4[wid][kk[e] & 255u], 1u);
  __syncthreads();
  hrev[t] = hist4[0][t] + hist4[1][t] + hist4[2][t] + hist4[3][t];
  __syncthreads();
  x = hrev[255 - t];
  #pragma unroll
  for (int o = 1; o < 64; o <<= 1){
    unsigned y = __shfl_up(x, o);
    if (lane >= o) x += y;
  }
  if (lane == 63) wtot[wid] = x;
  __syncthreads();
  #pragma unroll
  for (int w = 0; w < 4; w++) if (w < wid) x += wtot[w];
  suf[255 - t] = x;
  if (t == 0) suf[256] = 0u;
  __syncthreads();
  if (suf[t] >= rem && suf[t+1] < rem) selb = t;
  __syncthreads();
  const unsigned Tkey = ((unsigned)b1 << 8) | (unsigned)selb;
  const unsigned short tu = (Tkey & 0x8000u) ? (unsigned short)(Tkey & 0x7fffu)
                                             : (unsigned short)~Tkey;
  const float thr = u2hf(tu);

  float s = 0.f;
  #pragma unroll
  for (int e = 0; e < 16; e++)
    s += (v[e] >= thr) ? __expf(v[e] - m) : 0.f;
  s = wred_sum(s);
  if (lane == 0) red2[wid] = s;
  __syncthreads();
  if (t == 0){
    s = red2[0] + red2[1] + red2[2] + red2[3];
    mlthr[blockIdx.x] = make_float4(m, s, thr, 0.f);
  }
}

// ======== memory-head softmax over 64 scores: one wave per row ========
__global__ __launch_bounds__(256) void msoftmax64(const float* __restrict__ mscore,
                                                  _Float16* __restrict__ mprob){
  const int t = threadIdx.x, lane = t & 63, wid = t >> 6;
  const size_t row = (size_t)blockIdx.x * 4 + wid;
  float v = mscore[row*64 + lane];
  float m = wred_max(v);
  float e = expf(v - m);
  float s = wred_sum(e);
  mprob[row*64 + lane] = (_Float16)(e / s);
}

extern "C" void kernel_launch(void* const* d_in, const int* in_sizes, int n_in,
                              void* d_out, int out_size, void* d_ws, size_t ws_size,
                              hipStream_t stream)
{
  const float* x             = (const float*)d_in[0];
  const float* local_qkv_w   = (const float*)d_in[1];
  const float* sparse_qkv_w  = (const float*)d_in[2];
  const float* memory_bank   = (const float*)d_in[3];
  const float* memory_proj_w = (const float*)d_in[4];
  const float* mem_out_w     = (const float*)d_in[5];
  const float* mem_out_b     = (const float*)d_in[6];
  const float* pred_in_w     = (const float*)d_in[7];
  const float* pred_in_b     = (const float*)d_in[8];
  const float* pred1_w       = (const float*)d_in[9];
  const float* pred1_b       = (const float*)d_in[10];
  const float* pred2_w       = (const float*)d_in[11];
  const float* pred2_b       = (const float*)d_in[12];
  const float* warboss_w     = (const float*)d_in[13];
  const float* warboss_b     = (const float*)d_in[14];
  float* out = (float*)d_out;
  _Float16* Ph = (_Float16*)d_out;   // f16 PV partials [8][4096][256] = 16.8MB

  char* wsb = (char*)d_ws;
  _Float16*  scores_h = (_Float16*)wsb;                // [2][4096][4096] f16 (67MB)
  _Float16*  x_h      = (_Float16*)wsb;
  _Float16*  mem_cat  = (_Float16*)(wsb + 16777216);
  _Float16*  h_in     = (_Float16*)(wsb + 25165824);
  _Float16*  h1       = (_Float16*)(wsb + 29360128);
  float*     mscore   = (float*)(wsb + 37748736);
  _Float16*  mprob    = (_Float16*)(wsb + 39845888);
  _Float16*  qkv_l    = (_Float16*)(wsb + 67108864);   // [8192][768]
  _Float16*  qkv_s    = (_Float16*)(wsb + 79691776);   // [8192][768]
  _Float16*  Vt       = (_Float16*)(wsb + 92274688);   // [2][256][4096]
  _Float16*  comb     = (_Float16*)(wsb + 96468992);   // [8192][1024]
  _Float16*  lqkvT    = (_Float16*)(wsb + 113246208);  // [768][1024]
  _Float16*  sqkvT    = lqkvT  + 786432;
  _Float16*  mprojT   = sqkvT  + 786432;               // [256][1024]
  _Float16*  moutT    = mprojT + 262144;               // [256][512]
  _Float16*  pinT     = moutT  + 131072;               // [256][1024]
  _Float16*  p1T      = pinT   + 262144;               // [512][256]
  _Float16*  p2T      = p1T    + 131072;               // [256][512]
  _Float16*  wbT      = p2T    + 131072;               // [1024][1024]
  _Float16*  bank_h   = wbT    + 1048576;              // [64][256]
  _Float16*  bankT_h  = bank_h + 16384;                // [256][64]
  float4*    mlthr    = (float4*)(bankT_h + 16384);    // [2][4096] {m,l,thr}

  const dim3 blk(256);
  const float scale = 0.0625f;
  const long QZ  = (long)4096 * 768;
  const long VZ  = (long)256 * 4096;
  const long SZH = (long)4096 * 4096;

  // ---- casts / weight transposes ----
  cast_xh<<<dim3(2048), blk, 0, stream>>>(x, x_h, 1048576);
  cast_xh<<<dim3(8), blk, 0, stream>>>(memory_bank, bank_h, 2048);
  transpose_cast_w<<<dim3(24,32), blk, 0, stream>>>(local_qkv_w,  1024,  768, lqkvT);
  transpose_cast_w<<<dim3(24,32), blk, 0, stream>>>(sparse_qkv_w, 1024,  768, sqkvT);
  transpose_cast_w<<<dim3( 8,32), blk, 0, stream>>>(memory_proj_w,1024,  256, mprojT);
  transpose_cast_w<<<dim3( 8,16), blk, 0, stream>>>(mem_out_w,     512,  256, moutT);
  transpose_cast_w<<<dim3( 8,32), blk, 0, stream>>>(pred_in_w,    1024,  256, pinT);
  transpose_cast_w<<<dim3(16, 8), blk, 0, stream>>>(pred1_w,       256,  512, p1T);
  transpose_cast_w<<<dim3( 8,16), blk, 0, stream>>>(pred2_w,       512,  256, p2T);
  transpose_cast_w<<<dim3(32,32), blk, 0, stream>>>(warboss_w,    1024, 1024, wbT);
  transpose_cast_w<<<dim3( 8, 2), blk, 0, stream>>>(memory_bank,    64,  256, bankT_h);

  // ---- QKV projections (merged z=2: local / sparse) ----
  gemm_ht<128,128,1,0><<<dim3(6,64,2), blk, 0, stream>>>(x_h,0,1024, lqkvT,786432,1024,
                                                         qkv_l,6291456,768, 1024, 1.f, nullptr);

  // ---- memory head (GEMM chain) -> comb[:, 512:768] ----
  gemm_ht<64,64,1,0><<<dim3(4,128), blk, 0, stream>>>(x_h,0,1024, mprojT,0,1024, mem_cat,0,512, 1024, 1.f, nullptr);
  gemm_ht<64,64,0,0><<<dim3(1,128), blk, 0, stream>>>(mem_cat,0,512, bank_h,0,256, (void*)mscore,0,64, 256, 1.f, nullptr);
  msoftmax64<<<dim3(2048), blk, 0, stream>>>(mscore, mprob);
  gemm_ht<64,64,1,0><<<dim3(4,128), blk, 0, stream>>>(mprob,0,64, bankT_h,0,64, mem_cat+256,0,512, 64, 1.f, nullptr);
  gemm_ht<64,64,1,0><<<dim3(4,128), blk, 0, stream>>>(mem_cat,0,512, moutT,0,512, comb+512,0,1024, 512, 1.f, mem_out_b);

  // ---- prediction head -> comb[:, 768:1024] ----
  gemm_ht<64,64,1,0><<<dim3(4,128), blk, 0, stream>>>(x_h,0,1024, pinT,0,1024, h_in,0,256, 1024, 1.f, pred_in_b);
  gemm_ht<64,128,1,1><<<dim3(4,128), blk, 0, stream>>>(h_in,0,256, p1T,0,256, h1,0,512, 256, 1.f, pred1_b);
  gemm_ht<64,64,1,0><<<dim3(4,128), blk, 0, stream>>>(h1,0,512, p2T,0,512, comb+768,0,1024, 512, 1.f, pred2_b);

  // ---- local (full) attention -> comb[:, 0:256] ----
  transpose_h<<<dim3(8,128,2), blk, 0, stream>>>(qkv_l+512, QZ, 768, Vt, VZ, 4096);
  gemm_ht<128,128,1,0><<<dim3(32,32,2), blk, 0, stream>>>(qkv_l,QZ,768, qkv_l+256,QZ,768,
                                                          (void*)scores_h,SZH,4096, 256, scale, nullptr);
  rowstat_local<<<dim3(8192), blk, 0, stream>>>(scores_h, mlthr);
  gemm_pv_exp<64,256,0><<<dim3(1,64,8), blk, 0, stream>>>(scores_h,SZH,4096, Vt,VZ,4096, mlthr, Ph, 4, 1024);
  reduce4h<<<dim3(2048), blk, 0, stream>>>(Ph, mlthr, comb, 0, 524288);

  // ---- sparse (top-k) attention -> comb[:, 256:512] ----
  transpose_h<<<dim3(8,128,2), blk, 0, stream>>>(qkv_s+512, QZ, 768, Vt, VZ, 4096);
  gemm_ht<128,128,1,0><<<dim3(32,32,2), blk, 0, stream>>>(qkv_s,QZ,768, qkv_s+256,QZ,768,
                                                          (void*)scores_h,SZH,4096, 256, scale, nullptr);
  rowstat_sparse<<<dim3(8192), blk, 0, stream>>>(scores_h, mlthr, 409);
  gemm_pv_exp<64,256,1><<<dim3(1,64,8), blk, 0, stream>>>(scores_h,SZH,4096, Vt,VZ,4096, mlthr, Ph, 4, 1024);
  reduce4h<<<dim3(2048), blk, 0, stream>>>(Ph, mlthr, comb, 256, 524288);

  // ---- output projection (f32 out; overwrites the Ph scratch region) ----
  gemm_ht<128,128,0,0><<<dim3(8,64), blk, 0, stream>>>(comb,0,1024, wbT,0,1024, (void*)out,0,1024, 1024, 1.f, warboss_b);
}

// Round 18
// 377.614 us; speedup vs baseline: 1.1356x; 1.0116x over previous
//
#include <hip/hip_runtime.h>
#include <hip/hip_bf16.h>
#include <hip/hip_fp16.h>

typedef __attribute__((ext_vector_type(8))) _Float16 half8;
typedef __attribute__((ext_vector_type(4))) _Float16 half4v;
typedef __attribute__((ext_vector_type(4))) float f32x4;

__device__ __forceinline__ float wred_max(float v){
  #pragma unroll
  for (int o = 32; o; o >>= 1) v = fmaxf(v, __shfl_xor(v, o));
  return v;
}
__device__ __forceinline__ float wred_sum(float v){
  #pragma unroll
  for (int o = 32; o; o >>= 1) v += __shfl_xor(v, o);
  return v;
}
__device__ __forceinline__ unsigned short h2u(_Float16 h){
  unsigned short u;
  __builtin_memcpy(&u, &h, 2);
  return u;
}
__device__ __forceinline__ float u2hf(unsigned short u){
  _Float16 h;
  __builtin_memcpy(&h, &u, 2);
  return (float)h;
}
__device__ __forceinline__ _Float16 hexp16(_Float16 d){
  __half hd, he;
  __builtin_memcpy(&hd, &d, 2);
  he = hexp(hd);
  _Float16 r;
  __builtin_memcpy(&r, &he, 2);
  return r;
}

// T1: bijective XCD-aware block remap (chunked); identity when nwg % 8 != 0.
__device__ __forceinline__ void xcd_swz(int &bx, int &by, int &bz){
  const int gx = gridDim.x, gy = gridDim.y, gz = gridDim.z;
  const long nwg = (long)gx * gy * gz;
  if ((nwg & 7) != 0) return;
  long flat = bx + (long)gx * (by + (long)gy * bz);
  const long cpx = nwg >> 3;
  flat = (flat & 7) * cpx + (flat >> 3);
  bx = (int)(flat % gx); flat /= gx;
  by = (int)(flat % gy);
  bz = (int)(flat / gy);
}

#define GLOAD16(GP, LP) __builtin_amdgcn_global_load_lds( \
    (const __attribute__((address_space(1))) void*)(GP),  \
    (__attribute__((address_space(3))) void*)(LP), 16, 0, 0)

// ======== MFMA GEMM, 2-phase double-buffered: C = alpha * A @ B^T (+bias) ========
// sbias: per-z element stride on the bias vector (0 = shared bias).
template<int BM, int BN, int OUT_F16, int ACT>
__global__ __launch_bounds__(256) void gemm_ht(
    const _Float16* __restrict__ A, long saz, int lda,
    const _Float16* __restrict__ B, long sbz, int ldb,
    void* __restrict__ Cv, long scz, int ldc,
    int K, float alpha, const float* __restrict__ bias, long sbias)
{
  constexpr int FM = BM / 32, FN = BN / 32;
  __shared__ __align__(16) _Float16 Asl[2][BM * 32];
  __shared__ __align__(16) _Float16 Bsl[2][BN * 32];
  const int t = threadIdx.x;
  const int wid = t >> 6, lane = t & 63;
  const int wr = wid >> 1, wc = wid & 1;
  const int lr = lane & 15, kg = lane >> 4;
  int bx = blockIdx.x, by = blockIdx.y, bz = blockIdx.z;
  xcd_swz(bx, by, bz);
  A += (long)bz * saz;
  B += (long)bz * sbz;
  if (bias) bias += (long)bz * sbias;
  const long row0 = (long)by * BM;
  const long col0 = (long)bx * BN;

  const int arow_t = t >> 2, acol_t = (t & 3) * 8;

  auto stage = [&](int buf, int k0){
    #pragma unroll
    for (int r = 0; r < BM / 64; r++){
      const _Float16* gp = A + (row0 + r*64 + arow_t) * (long)lda + k0 + acol_t;
      GLOAD16(gp, (char*)Asl[buf] + r*4096 + wid*1024);
    }
    #pragma unroll
    for (int r = 0; r < BN / 64; r++){
      const _Float16* gp = B + (col0 + r*64 + arow_t) * (long)ldb + k0 + acol_t;
      GLOAD16(gp, (char*)Bsl[buf] + r*4096 + wid*1024);
    }
  };

  f32x4 acc[FM][FN];
  #pragma unroll
  for (int i = 0; i < FM; i++)
    #pragma unroll
    for (int j = 0; j < FN; j++)
      acc[i][j] = (f32x4){0.f, 0.f, 0.f, 0.f};

  stage(0, 0);
  __syncthreads();
  int cur = 0;
  for (int k0 = 0; k0 < K; k0 += 32){
    if (k0 + 32 < K) stage(cur ^ 1, k0 + 32);
    half8 af[FM], bfv[FN];
    #pragma unroll
    for (int i = 0; i < FM; i++)
      af[i] = *(const half8*)((const char*)Asl[cur] + (wr*(BM/2) + i*16 + lr)*64 + kg*16);
    #pragma unroll
    for (int j = 0; j < FN; j++)
      bfv[j] = *(const half8*)((const char*)Bsl[cur] + (wc*(BN/2) + j*16 + lr)*64 + kg*16);
    #pragma unroll
    for (int i = 0; i < FM; i++)
      #pragma unroll
      for (int j = 0; j < FN; j++)
        acc[i][j] = __builtin_amdgcn_mfma_f32_16x16x32_f16(af[i], bfv[j], acc[i][j], 0, 0, 0);
    __syncthreads();
    cur ^= 1;
  }

  _Float16* Ch = (_Float16*)Cv + (long)bz * scz;
  float*    Cf = (float*)Cv    + (long)bz * scz;
  #pragma unroll
  for (int i = 0; i < FM; i++){
    #pragma unroll
    for (int j = 0; j < FN; j++){
      #pragma unroll
      for (int q = 0; q < 4; q++){
        long rr = row0 + wr*(BM/2) + i*16 + kg*4 + q;
        long cc = col0 + wc*(BN/2) + j*16 + lr;
        float val = acc[i][j][q] * alpha;
        if (bias) val += bias[cc];
        if constexpr (ACT) val = 0.5f * val * (1.0f + erff(val * 0.70710678118654752f));
        if constexpr (OUT_F16) Ch[rr*(long)ldc + cc] = (_Float16)val;
        else                   Cf[rr*(long)ldc + cc] = val;
      }
    }
  }
}

// ======== PV GEMM, 2-phase dbuf, fused f16-exp/mask on A (reg-staged, write-late) ========
template<int BM, int BN, int SPARSE>
__global__ __launch_bounds__(256) void gemm_pv_exp(
    const _Float16* __restrict__ A, long saz, int lda,
    const _Float16* __restrict__ B, long sbz, int ldb,
    const float4* __restrict__ mlthr,
    _Float16* __restrict__ Ph, int nsplit, int Ksplit)
{
  constexpr int FM = BM / 32, FN = BN / 32;
  __shared__ __align__(16) _Float16 Asl[2][BM * 32];
  __shared__ __align__(16) _Float16 Bsl[2][BN * 32];
  const int t = threadIdx.x;
  const int wid = t >> 6, lane = t & 63;
  const int wr = wid >> 1, wc = wid & 1;
  const int lr = lane & 15, kg = lane >> 4;
  int bx = blockIdx.x, by = blockIdx.y, bz = blockIdx.z;
  xcd_swz(bx, by, bz);
  const int z = bz, batch = z / nsplit, split = z % nsplit;
  A += (long)batch * saz;
  B += (long)batch * sbz;
  _Float16* Pz = Ph + (size_t)z * (4096 * 256);
  const long row0 = (long)by * BM;
  const int Kbase = split * Ksplit;

  const long arow = row0 + (t >> 2);
  const float4 mt = mlthr[(long)batch*4096 + arow];
  const _Float16 mh  = (_Float16)mt.x;
  const _Float16 thh = (_Float16)mt.z;
  const _Float16* Ap = A + arow * (long)lda + Kbase + (t & 3) * 8;

  const int arow_t = t >> 2, acol_t = (t & 3) * 8;

  auto stageB = [&](int buf, int k0){
    #pragma unroll
    for (int r = 0; r < BN / 64; r++){
      const _Float16* gp = B + (r*64 + arow_t) * (long)ldb + Kbase + k0 + acol_t;
      GLOAD16(gp, (char*)Bsl[buf] + r*4096 + wid*1024);
    }
  };
  auto expw = [&](int buf, half8 ld){
    half8 st;
    #pragma unroll
    for (int e = 0; e < 8; e++){
      _Float16 ev = hexp16(ld[e] - mh);
      if constexpr (SPARSE) st[e] = (ld[e] >= thh) ? ev : (_Float16)0.f;
      else                  st[e] = ev;
    }
    *(half8*)((char*)Asl[buf] + t*16) = st;
  };

  f32x4 acc[FM][FN];
  #pragma unroll
  for (int i = 0; i < FM; i++)
    #pragma unroll
    for (int j = 0; j < FN; j++)
      acc[i][j] = (f32x4){0.f, 0.f, 0.f, 0.f};

  stageB(0, 0);
  expw(0, *(const half8*)(Ap + 0));
  __syncthreads();
  int cur = 0;
  for (int k0 = 0; k0 < Ksplit; k0 += 32){
    const bool more = (k0 + 32 < Ksplit);
    half8 lda_next;
    if (more){
      stageB(cur ^ 1, k0 + 32);
      lda_next = *(const half8*)(Ap + k0 + 32);
    }
    half8 af[FM], bfv[FN];
    #pragma unroll
    for (int i = 0; i < FM; i++)
      af[i] = *(const half8*)((const char*)Asl[cur] + (wr*(BM/2) + i*16 + lr)*64 + kg*16);
    #pragma unroll
    for (int j = 0; j < FN; j++)
      bfv[j] = *(const half8*)((const char*)Bsl[cur] + (wc*(BN/2) + j*16 + lr)*64 + kg*16);
    #pragma unroll
    for (int i = 0; i < FM; i++)
      #pragma unroll
      for (int j = 0; j < FN; j++)
        acc[i][j] = __builtin_amdgcn_mfma_f32_16x16x32_f16(af[i], bfv[j], acc[i][j], 0, 0, 0);
    if (more) expw(cur ^ 1, lda_next);
    __syncthreads();
    cur ^= 1;
  }

  #pragma unroll
  for (int i = 0; i < FM; i++)
    #pragma unroll
    for (int j = 0; j < FN; j++)
      #pragma unroll
      for (int q = 0; q < 4; q++){
        long rr = row0 + wr*(BM/2) + i*16 + kg*4 + q;
        long cc = wc*(BN/2) + j*16 + lr;
        Pz[rr*256 + cc] = (_Float16)acc[i][j][q];
      }
}

// ======== sum 4 f16 partials, divide by l -> f16 comb at column offset ========
__global__ __launch_bounds__(256) void reduce4h(const _Float16* __restrict__ Ph,
                                                const float4* __restrict__ mlthr,
                                                _Float16* __restrict__ dst, int coff, int nq){
  int i = blockIdx.x * 256 + threadIdx.x;
  if (i >= nq) return;
  int b = i >> 18;
  int r = i & 262143;
  int row = r >> 6, col4 = r & 63;
  float sx = 0.f, sy = 0.f, sz = 0.f, sw = 0.f;
  #pragma unroll
  for (int sp = 0; sp < 4; sp++){
    half4v p = *(const half4v*)(Ph + (((size_t)(b*4 + sp)*4096 + row)*256 + col4*4));
    sx += (float)p[0]; sy += (float)p[1]; sz += (float)p[2]; sw += (float)p[3];
  }
  const float inv = 1.0f / mlthr[(long)b*4096 + row].y;
  half4v o;
  o[0] = (_Float16)(sx*inv); o[1] = (_Float16)(sy*inv);
  o[2] = (_Float16)(sz*inv); o[3] = (_Float16)(sw*inv);
  *(half4v*)(dst + ((size_t)b*4096 + row)*1024 + coff + col4*4) = o;
}

// ======== zero-fill small f32 buffer ========
__global__ __launch_bounds__(256) void zero_f32(float* __restrict__ p, int n){
  int i = blockIdx.x * 256 + threadIdx.x;
  if (i < n) p[i] = 0.f;
}

// ======== cast f32 -> f16 (8 elems/thread) ========
__global__ __launch_bounds__(256) void cast_xh(const float* __restrict__ in,
                                               _Float16* __restrict__ out, int n8){
  int i = blockIdx.x * 256 + threadIdx.x;
  const int stride = gridDim.x * 256;
  for (; i < n8; i += stride){
    float4 a = ((const float4*)in)[2*i];
    float4 b = ((const float4*)in)[2*i + 1];
    half8 o;
    o[0]=(_Float16)a.x; o[1]=(_Float16)a.y; o[2]=(_Float16)a.z; o[3]=(_Float16)a.w;
    o[4]=(_Float16)b.x; o[5]=(_Float16)b.y; o[6]=(_Float16)b.z; o[7]=(_Float16)b.w;
    *(half8*)(out + (size_t)i*8) = o;
  }
}

// ======== transpose+cast weight: in (R x C) f32 -> out (C x R) f16 ========
__global__ __launch_bounds__(256) void transpose_cast_w(const float* __restrict__ in, int R, int C,
                                                        _Float16* __restrict__ out){
  __shared__ float tile[32][33];
  const int c0 = blockIdx.x * 32, r0 = blockIdx.y * 32;
  const int tx = threadIdx.x & 31, ty = threadIdx.x >> 5;
  #pragma unroll
  for (int i = 0; i < 32; i += 8)
    tile[ty+i][tx] = in[(size_t)(r0+ty+i)*C + c0+tx];
  __syncthreads();
  #pragma unroll
  for (int i = 0; i < 32; i += 8)
    out[(size_t)(c0+ty+i)*R + r0+tx] = (_Float16)tile[tx][ty+i];
}

// ======== f16 transpose: in (R x C, ld_in) -> out (C x R, ld_out), z-batched ========
__global__ __launch_bounds__(256) void transpose_h(
    const _Float16* __restrict__ in, long in_z, int ld_in,
    _Float16* __restrict__ out, long out_z, int ld_out)
{
  __shared__ _Float16 tile[32][34];
  const _Float16* ip = in + (long)blockIdx.z * in_z;
  _Float16* op = out + (long)blockIdx.z * out_z;
  const int c0 = blockIdx.x * 32, r0 = blockIdx.y * 32;
  const int tx = threadIdx.x & 31, ty = threadIdx.x >> 5;
  #pragma unroll
  for (int i = 0; i < 32; i += 8)
    tile[ty+i][tx] = ip[(long)(r0+ty+i)*ld_in + c0+tx];
  __syncthreads();
  #pragma unroll
  for (int i = 0; i < 32; i += 8)
    op[(long)(c0+ty+i)*ld_out + r0+tx] = tile[tx][ty+i];
}

// ======== rowstat (local): m = rowmax, l = sum exp(v-m); read-only ========
__global__ __launch_bounds__(256) void rowstat_local(const _Float16* __restrict__ sc,
                                                     float4* __restrict__ mlthr){
  __shared__ float red[4], red2[4];
  const int t = threadIdx.x, lane = t & 63, wid = t >> 6;
  const _Float16* p = sc + (size_t)blockIdx.x * 4096;
  half8 a = ((const half8*)p)[t*2];
  half8 b = ((const half8*)p)[t*2 + 1];
  float v[16];
  #pragma unroll
  for (int e = 0; e < 8; e++){ v[e] = (float)a[e]; v[8+e] = (float)b[e]; }
  float m = v[0];
  #pragma unroll
  for (int e = 1; e < 16; e++) m = fmaxf(m, v[e]);
  m = wred_max(m);
  if (lane == 0) red[wid] = m;
  __syncthreads();
  m = fmaxf(fmaxf(red[0], red[1]), fmaxf(red[2], red[3]));
  float s = 0.f;
  #pragma unroll
  for (int e = 0; e < 16; e++) s += __expf(v[e] - m);
  s = wred_sum(s);
  if (lane == 0) red2[wid] = s;
  __syncthreads();
  if (t == 0){
    s = red2[0] + red2[1] + red2[2] + red2[3];
    mlthr[blockIdx.x] = make_float4(m, s, -60000.0f, 0.f);
  }
}

// ======== rowstat (sparse): exact top-k threshold (2x8-bit radix on u16 keys) ========
__global__ __launch_bounds__(256) void rowstat_sparse(const _Float16* __restrict__ sc,
                                                      float4* __restrict__ mlthr, int ksel){
  __shared__ unsigned hist4[4][256];
  __shared__ unsigned hrev[256];
  __shared__ unsigned suf[257];
  __shared__ unsigned wtot[4];
  __shared__ int selb;
  __shared__ float red[4], red2[4];
  const int t = threadIdx.x, lane = t & 63, wid = t >> 6;
  const _Float16* p = sc + (size_t)blockIdx.x * 4096;
  half8 a = ((const half8*)p)[t*2];
  half8 b = ((const half8*)p)[t*2 + 1];
  float v[16]; unsigned kk[16];
  #pragma unroll
  for (int e = 0; e < 8; e++){
    unsigned short u0 = h2u(a[e]);
    unsigned short u1 = h2u(b[e]);
    kk[e]   = (u0 & 0x8000u) ? (unsigned)(unsigned short)~u0 : (unsigned)(u0 | 0x8000u);
    kk[8+e] = (u1 & 0x8000u) ? (unsigned)(unsigned short)~u1 : (unsigned)(u1 | 0x8000u);
    v[e] = (float)a[e]; v[8+e] = (float)b[e];
  }
  float m = v[0];
  #pragma unroll
  for (int e = 1; e < 16; e++) m = fmaxf(m, v[e]);
  m = wred_max(m);
  if (lane == 0) red[wid] = m;
  __syncthreads();
  m = fmaxf(fmaxf(red[0], red[1]), fmaxf(red[2], red[3]));

  // ---- pass 1: high byte ----
  ((uint4*)hist4)[t] = (uint4){0u,0u,0u,0u};
  __syncthreads();
  #pragma unroll
  for (int e = 0; e < 16; e++) atomicAdd(&hist4[wid][kk[e] >> 8], 1u);
  __syncthreads();
  hrev[t] = hist4[0][t] + hist4[1][t] + hist4[2][t] + hist4[3][t];
  __syncthreads();
  unsigned x = hrev[255 - t];
  #pragma unroll
  for (int o = 1; o < 64; o <<= 1){
    unsigned y = __shfl_up(x, o);
    if (lane >= o) x += y;
  }
  if (lane == 63) wtot[wid] = x;
  __syncthreads();
  #pragma unroll
  for (int w = 0; w < 4; w++) if (w < wid) x += wtot[w];
  suf[255 - t] = x;
  if (t == 0) suf[256] = 0u;
  __syncthreads();
  const unsigned ku = (unsigned)ksel;
  if (suf[t] >= ku && suf[t+1] < ku) selb = t;
  __syncthreads();
  const int b1 = selb;
  const unsigned rem = ku - suf[b1+1];
  __syncthreads();

  // ---- pass 2: low byte among high==b1 ----
  ((uint4*)hist4)[t] = (uint4){0u,0u,0u,0u};
  __syncthreads();
  #pragma unroll
  for (int e = 0; e < 16; e++)
    if ((int)(kk[e] >> 8) == b1) atomicAdd(&hist4[wid][kk[e] & 255u], 1u);
  __syncthreads();
  hrev[t] = hist4[0][t] + hist4[1][t] + hist4[2][t] + hist4[3][t];
  __syncthreads();
  x = hrev[255 - t];
  #pragma unroll
  for (int o = 1; o < 64; o <<= 1){
    unsigned y = __shfl_up(x, o);
    if (lane >= o) x += y;
  }
  if (lane == 63) wtot[wid] = x;
  __syncthreads();
  #pragma unroll
  for (int w = 0; w < 4; w++) if (w < wid) x += wtot[w];
  suf[255 - t] = x;
  if (t == 0) suf[256] = 0u;
  __syncthreads();
  if (suf[t] >= rem && suf[t+1] < rem) selb = t;
  __syncthreads();
  const unsigned Tkey = ((unsigned)b1 << 8) | (unsigned)selb;
  const unsigned short tu = (Tkey & 0x8000u) ? (unsigned short)(Tkey & 0x7fffu)
                                             : (unsigned short)~Tkey;
  const float thr = u2hf(tu);

  float s = 0.f;
  #pragma unroll
  for (int e = 0; e < 16; e++)
    s += (v[e] >= thr) ? __expf(v[e] - m) : 0.f;
  s = wred_sum(s);
  if (lane == 0) red2[wid] = s;
  __syncthreads();
  if (t == 0){
    s = red2[0] + red2[1] + red2[2] + red2[3];
    mlthr[blockIdx.x] = make_float4(m, s, thr, 0.f);
  }
}

// ======== memory-head softmax over 64 scores: one wave per row ========
__global__ __launch_bounds__(256) void msoftmax64(const float* __restrict__ mscore,
                                                  _Float16* __restrict__ mprob){
  const int t = threadIdx.x, lane = t & 63, wid = t >> 6;
  const size_t row = (size_t)blockIdx.x * 4 + wid;
  float v = mscore[row*64 + lane];
  float m = wred_max(v);
  float e = expf(v - m);
  float s = wred_sum(e);
  mprob[row*64 + lane] = (_Float16)(e / s);
}

extern "C" void kernel_launch(void* const* d_in, const int* in_sizes, int n_in,
                              void* d_out, int out_size, void* d_ws, size_t ws_size,
                              hipStream_t stream)
{
  const float* x             = (const float*)d_in[0];
  const float* local_qkv_w   = (const float*)d_in[1];
  const float* sparse_qkv_w  = (const float*)d_in[2];
  const float* memory_bank   = (const float*)d_in[3];
  const float* memory_proj_w = (const float*)d_in[4];
  const float* mem_out_w     = (const float*)d_in[5];
  const float* mem_out_b     = (const float*)d_in[6];
  const float* pred_in_w     = (const float*)d_in[7];
  const float* pred_in_b     = (const float*)d_in[8];
  const float* pred1_w       = (const float*)d_in[9];
  const float* pred1_b       = (const float*)d_in[10];
  const float* pred2_w       = (const float*)d_in[11];
  const float* pred2_b       = (const float*)d_in[12];
  const float* warboss_w     = (const float*)d_in[13];
  const float* warboss_b     = (const float*)d_in[14];
  float* out = (float*)d_out;
  _Float16* Ph = (_Float16*)d_out;   // f16 PV partials [8][4096][256] = 16.8MB

  // Region A [0, 67,108,864) layout (bytes):
  //   x_h      [0,        16777216)  f16 [8192][1024]
  //   mem_cat  [16777216, 25165824)  f16 [8192][512]  (cols 0:256 xproj, 256:512 retrieved)
  //   h1       [25165824, 33554432)  f16 [8192][512]  (adjacent to mem_cat: saz=4194304)
  //   h_in     [33554432, 41943040)  f16 [8192][512]  (valid cols 0:256, ldc 512)
  //   mscore   [41943040, 44040192)  f32 [8192][64]
  //   mprob    [44040192, 45088768)  f16 [8192][64]
  //   (scores_h overlays [0, 67108864) during attention phases)
  char* wsb = (char*)d_ws;
  _Float16*  scores_h = (_Float16*)wsb;
  _Float16*  x_h      = (_Float16*)wsb;
  _Float16*  mem_cat  = (_Float16*)(wsb + 16777216);
  _Float16*  h1       = (_Float16*)(wsb + 25165824);
  _Float16*  h_in     = (_Float16*)(wsb + 33554432);
  float*     mscore   = (float*)(wsb + 41943040);
  _Float16*  mprob    = (_Float16*)(wsb + 44040192);
  _Float16*  qkv_l    = (_Float16*)(wsb + 67108864);   // [8192][768]
  _Float16*  qkv_s    = (_Float16*)(wsb + 79691776);   // [8192][768]
  _Float16*  Vt       = (_Float16*)(wsb + 92274688);   // [2][256][4096]
  _Float16*  comb     = (_Float16*)(wsb + 96468992);   // [8192][1024]
  _Float16*  lqkvT    = (_Float16*)(wsb + 113246208);  // [768][1024]
  _Float16*  sqkvT    = lqkvT  + 786432;               // [768][1024]
  _Float16*  mprojT   = sqkvT  + 786432;               // [256][1024]
  _Float16*  pinT     = mprojT + 262144;               // [256][1024] (adjacent: sbz=262144)
  _Float16*  moutT    = pinT   + 262144;               // [256][512]
  _Float16*  p2T      = moutT  + 131072;               // [256][512]  (adjacent: sbz=131072)
  _Float16*  p1T      = p2T    + 131072;               // [512][256]
  _Float16*  wbT      = p1T    + 131072;               // [1024][1024]
  _Float16*  bank_h   = wbT    + 1048576;              // [64][256]
  _Float16*  bankT_h  = bank_h + 16384;                // [256][64]
  float4*    mlthr    = (float4*)(bankT_h + 16384);    // [2][4096] {m,l,thr}
  float*     bias_stg = (float*)(mlthr + 8192);        // [4][256]: zeros|pred_in_b|mem_out_b|pred2_b

  const dim3 blk(256);
  const float scale = 0.0625f;
  const long QZ  = (long)4096 * 768;
  const long VZ  = (long)256 * 4096;
  const long SZH = (long)4096 * 4096;

  // ---- bias staging (zeros + d2d copies) ----
  zero_f32<<<dim3(1), blk, 0, stream>>>(bias_stg, 256);
  hipMemcpyAsync(bias_stg + 256, pred_in_b, 256*sizeof(float), hipMemcpyDeviceToDevice, stream);
  hipMemcpyAsync(bias_stg + 512, mem_out_b, 256*sizeof(float), hipMemcpyDeviceToDevice, stream);
  hipMemcpyAsync(bias_stg + 768, pred2_b,   256*sizeof(float), hipMemcpyDeviceToDevice, stream);

  // ---- casts / weight transposes ----
  cast_xh<<<dim3(2048), blk, 0, stream>>>(x, x_h, 1048576);
  cast_xh<<<dim3(8), blk, 0, stream>>>(memory_bank, bank_h, 2048);
  transpose_cast_w<<<dim3(24,32), blk, 0, stream>>>(local_qkv_w,  1024,  768, lqkvT);
  transpose_cast_w<<<dim3(24,32), blk, 0, stream>>>(sparse_qkv_w, 1024,  768, sqkvT);
  transpose_cast_w<<<dim3( 8,32), blk, 0, stream>>>(memory_proj_w,1024,  256, mprojT);
  transpose_cast_w<<<dim3( 8,16), blk, 0, stream>>>(mem_out_w,     512,  256, moutT);
  transpose_cast_w<<<dim3( 8,32), blk, 0, stream>>>(pred_in_w,    1024,  256, pinT);
  transpose_cast_w<<<dim3(16, 8), blk, 0, stream>>>(pred1_w,       256,  512, p1T);
  transpose_cast_w<<<dim3( 8,16), blk, 0, stream>>>(pred2_w,       512,  256, p2T);
  transpose_cast_w<<<dim3(32,32), blk, 0, stream>>>(warboss_w,    1024, 1024, wbT);
  transpose_cast_w<<<dim3( 8, 2), blk, 0, stream>>>(memory_bank,    64,  256, bankT_h);

  // ---- QKV projections (merged z=2: local / sparse) ----
  gemm_ht<128,128,1,0><<<dim3(6,64,2), blk, 0, stream>>>(x_h,0,1024, lqkvT,786432,1024,
                                                         qkv_l,6291456,768, 1024, 1.f, nullptr, 0);

  // ---- merged head input projections (z=2: x@mproj -> mem_cat | x@pred_in+b -> h_in) ----
  gemm_ht<64,64,1,0><<<dim3(4,128,2), blk, 0, stream>>>(x_h,0,1024, mprojT,262144,1024,
                                                        mem_cat,8388608,512, 1024, 1.f, bias_stg, 256);

  // ---- memory-head middle: scores vs bank, softmax, retrieve ----
  gemm_ht<64,64,0,0><<<dim3(1,128), blk, 0, stream>>>(mem_cat,0,512, bank_h,0,256, (void*)mscore,0,64, 256, 1.f, nullptr, 0);
  msoftmax64<<<dim3(2048), blk, 0, stream>>>(mscore, mprob);
  gemm_ht<64,64,1,0><<<dim3(4,128), blk, 0, stream>>>(mprob,0,64, bankT_h,0,64, mem_cat+256,0,512, 64, 1.f, nullptr, 0);
  // ---- prediction-head middle: h1 = gelu(h_in@p1T + b) ----
  gemm_ht<64,128,1,1><<<dim3(4,128), blk, 0, stream>>>(h_in,0,512, p1T,0,256, h1,0,512, 256, 1.f, pred1_b, 0);

  // ---- merged head output projections (z=2: mem_cat@mout+b -> comb+512 | h1@p2T+b -> comb+768) ----
  gemm_ht<64,64,1,0><<<dim3(4,128,2), blk, 0, stream>>>(mem_cat,4194304,512, moutT,131072,512,
                                                        comb+512,256,1024, 512, 1.f, bias_stg+512, 256);

  // ---- local (full) attention -> comb[:, 0:256] ----
  transpose_h<<<dim3(8,128,2), blk, 0, stream>>>(qkv_l+512, QZ, 768, Vt, VZ, 4096);
  gemm_ht<128,128,1,0><<<dim3(32,32,2), blk, 0, stream>>>(qkv_l,QZ,768, qkv_l+256,QZ,768,
                                                          (void*)scores_h,SZH,4096, 256, scale, nullptr, 0);
  rowstat_local<<<dim3(8192), blk, 0, stream>>>(scores_h, mlthr);
  gemm_pv_exp<64,256,0><<<dim3(1,64,8), blk, 0, stream>>>(scores_h,SZH,4096, Vt,VZ,4096, mlthr, Ph, 4, 1024);
  reduce4h<<<dim3(2048), blk, 0, stream>>>(Ph, mlthr, comb, 0, 524288);

  // ---- sparse (top-k) attention -> comb[:, 256:512] ----
  transpose_h<<<dim3(8,128,2), blk, 0, stream>>>(qkv_s+512, QZ, 768, Vt, VZ, 4096);
  gemm_ht<128,128,1,0><<<dim3(32,32,2), blk, 0, stream>>>(qkv_s,QZ,768, qkv_s+256,QZ,768,
                                                          (void*)scores_h,SZH,4096, 256, scale, nullptr, 0);
  rowstat_sparse<<<dim3(8192), blk, 0, stream>>>(scores_h, mlthr, 409);
  gemm_pv_exp<64,256,1><<<dim3(1,64,8), blk, 0, stream>>>(scores_h,SZH,4096, Vt,VZ,4096, mlthr, Ph, 4, 1024);
  reduce4h<<<dim3(2048), blk, 0, stream>>>(Ph, mlthr, comb, 256, 524288);

  // ---- output projection (f32 out; overwrites the Ph scratch region) ----
  gemm_ht<128,128,0,0><<<dim3(8,64), blk, 0, stream>>>(comb,0,1024, wbT,0,1024, (void*)out,0,1024, 1024, 1.f, warboss_b, 0);
}